// Round 1
// baseline (1226.956 us; speedup 1.0000x reference)
//
#include <hip/hip_runtime.h>
#include <cstdint>
#include <cstddef>

#define B_   2
#define S_   2048
#define D_   1024
#define H_   16
#define DK_  64
#define NEG_INF_F (-3.4028234663852886e38f)

// ---------------------------------------------------------------------------
// k_proj: Y = A @ W^T + bias.   A:[M][K] row-major, W:[N][K] row-major.
// Tile 128x128, BK=32, 256 threads, 8x8 per thread.
// HEAD_OUT: write Y in [B][H][S][DK] layout (QKV proj); else plain [M][N].
// ---------------------------------------------------------------------------
template <bool HEAD_OUT>
__global__ __launch_bounds__(256) void k_proj(const float* __restrict__ A,
                                              const float* __restrict__ W,
                                              const float* __restrict__ bias,
                                              float* __restrict__ Y,
                                              int M, int N, int K) {
  __shared__ __align__(16) float As[32][132];
  __shared__ __align__(16) float Bs[32][132];
  const int tid = threadIdx.x;
  const int tx = tid & 15, ty = tid >> 4;
  const int m0 = blockIdx.y * 128, n0 = blockIdx.x * 128;

  float acc[8][8] = {};

  for (int kt = 0; kt < K; kt += 32) {
#pragma unroll
    for (int i = 0; i < 4; ++i) {
      int li = tid + i * 256;        // float4 index within 128x32 tile
      int row = li >> 3, c4 = li & 7;
      float4 v = *(const float4*)(A + (size_t)(m0 + row) * K + kt + c4 * 4);
      As[c4 * 4 + 0][row] = v.x; As[c4 * 4 + 1][row] = v.y;
      As[c4 * 4 + 2][row] = v.z; As[c4 * 4 + 3][row] = v.w;
      float4 w = *(const float4*)(W + (size_t)(n0 + row) * K + kt + c4 * 4);
      Bs[c4 * 4 + 0][row] = w.x; Bs[c4 * 4 + 1][row] = w.y;
      Bs[c4 * 4 + 2][row] = w.z; Bs[c4 * 4 + 3][row] = w.w;
    }
    __syncthreads();
#pragma unroll
    for (int kk = 0; kk < 32; ++kk) {
      float4 a0 = *(const float4*)&As[kk][ty * 8];
      float4 a1 = *(const float4*)&As[kk][ty * 8 + 4];
      float4 b0 = *(const float4*)&Bs[kk][tx * 8];
      float4 b1 = *(const float4*)&Bs[kk][tx * 8 + 4];
      float av[8] = {a0.x, a0.y, a0.z, a0.w, a1.x, a1.y, a1.z, a1.w};
      float bv[8] = {b0.x, b0.y, b0.z, b0.w, b1.x, b1.y, b1.z, b1.w};
#pragma unroll
      for (int i = 0; i < 8; ++i)
#pragma unroll
        for (int j = 0; j < 8; ++j) acc[i][j] = fmaf(av[i], bv[j], acc[i][j]);
    }
    __syncthreads();
  }

#pragma unroll
  for (int i = 0; i < 8; ++i) {
    int m = m0 + ty * 8 + i;
#pragma unroll
    for (int j = 0; j < 8; ++j) {
      int n = n0 + tx * 8 + j;
      float v = acc[i][j] + bias[n];
      if (HEAD_OUT) {
        int b = m >> 11, s = m & (S_ - 1);
        int h = n >> 6, dk = n & (DK_ - 1);
        Y[(((size_t)(b * H_ + h)) * S_ + s) * DK_ + dk] = v;
      } else {
        Y[(size_t)m * N + n] = v;
      }
    }
  }
}

// ---------------------------------------------------------------------------
// k_scores: raw scaled scores = (Q @ K^T) / sqrt(DK) per (b,h), written into
// the alpha region of d_out.  Causal-masked tiles are skipped entirely.
// ---------------------------------------------------------------------------
__global__ __launch_bounds__(256) void k_scores(const float* __restrict__ Qm,
                                                const float* __restrict__ Km,
                                                float* __restrict__ alpha,
                                                const int* __restrict__ causal_p) {
  __shared__ __align__(16) float As[32][132];
  __shared__ __align__(16) float Bs[32][132];
  const int z = blockIdx.z;                    // b*H + h
  const int q0 = blockIdx.y * 128, k0 = blockIdx.x * 128;
  if (*causal_p && k0 >= q0 + 128) return;     // fully masked tile

  const float* A = Qm + (size_t)z * S_ * DK_;
  const float* Bb = Km + (size_t)z * S_ * DK_;
  const int tid = threadIdx.x;
  const int tx = tid & 15, ty = tid >> 4;

  float acc[8][8] = {};

  for (int kt = 0; kt < DK_; kt += 32) {
#pragma unroll
    for (int i = 0; i < 4; ++i) {
      int li = tid + i * 256;
      int row = li >> 3, c4 = li & 7;
      float4 v = *(const float4*)(A + (size_t)(q0 + row) * DK_ + kt + c4 * 4);
      As[c4 * 4 + 0][row] = v.x; As[c4 * 4 + 1][row] = v.y;
      As[c4 * 4 + 2][row] = v.z; As[c4 * 4 + 3][row] = v.w;
      float4 w = *(const float4*)(Bb + (size_t)(k0 + row) * DK_ + kt + c4 * 4);
      Bs[c4 * 4 + 0][row] = w.x; Bs[c4 * 4 + 1][row] = w.y;
      Bs[c4 * 4 + 2][row] = w.z; Bs[c4 * 4 + 3][row] = w.w;
    }
    __syncthreads();
#pragma unroll
    for (int kk = 0; kk < 32; ++kk) {
      float4 a0 = *(const float4*)&As[kk][ty * 8];
      float4 a1 = *(const float4*)&As[kk][ty * 8 + 4];
      float4 b0 = *(const float4*)&Bs[kk][tx * 8];
      float4 b1 = *(const float4*)&Bs[kk][tx * 8 + 4];
      float av[8] = {a0.x, a0.y, a0.z, a0.w, a1.x, a1.y, a1.z, a1.w};
      float bv[8] = {b0.x, b0.y, b0.z, b0.w, b1.x, b1.y, b1.z, b1.w};
#pragma unroll
      for (int i = 0; i < 8; ++i)
#pragma unroll
        for (int j = 0; j < 8; ++j) acc[i][j] = fmaf(av[i], bv[j], acc[i][j]);
    }
    __syncthreads();
  }

  float* outr = alpha + (size_t)z * S_ * S_;
  const float scale = 0.125f;  // 1/sqrt(64)
#pragma unroll
  for (int i = 0; i < 8; ++i) {
    size_t off = (size_t)(q0 + ty * 8 + i) * S_ + k0 + tx * 8;
    float4 o0 = make_float4(acc[i][0] * scale, acc[i][1] * scale,
                            acc[i][2] * scale, acc[i][3] * scale);
    float4 o1 = make_float4(acc[i][4] * scale, acc[i][5] * scale,
                            acc[i][6] * scale, acc[i][7] * scale);
    *(float4*)(outr + off) = o0;
    *(float4*)(outr + off + 4) = o1;
  }
}

// ---------------------------------------------------------------------------
// k_softmax: in-place row softmax over alpha region, one block per row.
// Applies padding mask (==1 -> NEG_INF) and causal bound; zero-fills k>=kmax.
// ---------------------------------------------------------------------------
__global__ __launch_bounds__(256) void k_softmax(float* __restrict__ alpha,
                                                 const int* __restrict__ pad,
                                                 const int* __restrict__ causal_p) {
  const int row = blockIdx.x;                 // 0 .. B*H*S-1
  const int q = row & (S_ - 1);
  const int b = row / (H_ * S_);
  const int causal = *causal_p;
  const int kmax = causal ? (q + 1) : S_;
  float* rp = alpha + (size_t)row * S_;
  const int tid = threadIdx.x;
  const int n4 = (kmax + 3) >> 2;

  float v[8];
  int have[2] = {-1, -1};
  int cnt = 0;
  float mx = NEG_INF_F;

  for (int i4 = tid; i4 < n4; i4 += 256) {
    float4 sv = ((const float4*)rp)[i4];
    float f[4] = {sv.x, sv.y, sv.z, sv.w};
#pragma unroll
    for (int c = 0; c < 4; ++c) {
      int k = i4 * 4 + c;
      bool ok = (k < kmax) && (pad[b * S_ + k] == 0);
      float s = ok ? f[c] : NEG_INF_F;
      v[cnt * 4 + c] = s;
      mx = fmaxf(mx, s);
    }
    have[cnt] = i4;
    ++cnt;
  }

  // block reduce max
  __shared__ float redmax[4];
  __shared__ float redsum[4];
#pragma unroll
  for (int off = 32; off >= 1; off >>= 1) mx = fmaxf(mx, __shfl_xor(mx, off));
  if ((tid & 63) == 0) redmax[tid >> 6] = mx;
  __syncthreads();
  mx = fmaxf(fmaxf(redmax[0], redmax[1]), fmaxf(redmax[2], redmax[3]));

  float sum = 0.f;
  for (int u = 0; u < cnt; ++u) {
#pragma unroll
    for (int c = 0; c < 4; ++c) {
      float e = __expf(v[u * 4 + c] - mx);
      v[u * 4 + c] = e;
      sum += e;
    }
  }
#pragma unroll
  for (int off = 32; off >= 1; off >>= 1) sum += __shfl_xor(sum, off);
  if ((tid & 63) == 0) redsum[tid >> 6] = sum;
  __syncthreads();
  sum = redsum[0] + redsum[1] + redsum[2] + redsum[3];

  const float inv = 1.0f / sum;
  for (int u = 0; u < cnt; ++u) {
    int i4 = have[u];
    float o[4];
#pragma unroll
    for (int c = 0; c < 4; ++c) {
      int k = i4 * 4 + c;
      o[c] = (k < kmax) ? v[u * 4 + c] * inv : 0.f;
    }
    ((float4*)rp)[i4] = make_float4(o[0], o[1], o[2], o[3]);
  }
  for (int i4 = n4 + tid; i4 < (S_ >> 2); i4 += 256)
    ((float4*)rp)[i4] = make_float4(0.f, 0.f, 0.f, 0.f);
}

// ---------------------------------------------------------------------------
// k_pv: context = alpha @ V per (b,h).  Tile 64x64, BK=32, 4x4 per thread.
// Causal bound on K-loop.  Writes context in [B][S][D] layout.
// ---------------------------------------------------------------------------
__global__ __launch_bounds__(256) void k_pv(const float* __restrict__ alpha,
                                            const float* __restrict__ V,
                                            float* __restrict__ C,
                                            const int* __restrict__ causal_p) {
  __shared__ __align__(16) float As[32][68];
  __shared__ __align__(16) float Bs[32][68];
  const int z = blockIdx.z;           // b*H + h
  const int q0 = blockIdx.y * 64;
  const float* A = alpha + (size_t)z * S_ * S_;   // [S][S]
  const float* Bb = V + (size_t)z * S_ * DK_;     // [S][DK]
  const int tid = threadIdx.x;
  const int tx = tid & 15, ty = tid >> 4;
  const int kend = (*causal_p) ? (q0 + 64) : S_;

  float acc[4][4] = {};

  for (int kt = 0; kt < kend; kt += 32) {
#pragma unroll
    for (int i = 0; i < 2; ++i) {
      int li = tid + i * 256;
      int row = li >> 3, c4 = li & 7;       // A tile: 64 rows x 32 k
      float4 v = *(const float4*)(A + (size_t)(q0 + row) * S_ + kt + c4 * 4);
      As[c4 * 4 + 0][row] = v.x; As[c4 * 4 + 1][row] = v.y;
      As[c4 * 4 + 2][row] = v.z; As[c4 * 4 + 3][row] = v.w;
      int r2 = li >> 4, c2 = li & 15;       // B tile: 32 k x 64 dk
      float4 w = *(const float4*)(Bb + (size_t)(kt + r2) * DK_ + c2 * 4);
      *(float4*)&Bs[r2][c2 * 4] = w;
    }
    __syncthreads();
#pragma unroll
    for (int kk = 0; kk < 32; ++kk) {
      float4 a = *(const float4*)&As[kk][ty * 4];
      float4 b = *(const float4*)&Bs[kk][tx * 4];
      float av[4] = {a.x, a.y, a.z, a.w};
      float bv[4] = {b.x, b.y, b.z, b.w};
#pragma unroll
      for (int i = 0; i < 4; ++i)
#pragma unroll
        for (int j = 0; j < 4; ++j) acc[i][j] = fmaf(av[i], bv[j], acc[i][j]);
    }
    __syncthreads();
  }

  const int b = z >> 4, h = z & (H_ - 1);
#pragma unroll
  for (int i = 0; i < 4; ++i) {
    int q = q0 + ty * 4 + i;
    float4 o = make_float4(acc[i][0], acc[i][1], acc[i][2], acc[i][3]);
    *(float4*)(C + ((size_t)(b * S_ + q)) * D_ + h * DK_ + tx * 4) = o;
  }
}

// ---------------------------------------------------------------------------
extern "C" void kernel_launch(void* const* d_in, const int* in_sizes, int n_in,
                              void* d_out, int out_size, void* d_ws,
                              size_t ws_size, hipStream_t stream) {
  (void)in_sizes; (void)n_in; (void)out_size; (void)ws_size;
  const float* X  = (const float*)d_in[0];
  const float* Wq = (const float*)d_in[1];
  const float* bq = (const float*)d_in[2];
  const float* Wk = (const float*)d_in[3];
  const float* bk = (const float*)d_in[4];
  const float* Wv = (const float*)d_in[5];
  const float* bv = (const float*)d_in[6];
  const float* Wo = (const float*)d_in[7];
  const float* bo = (const float*)d_in[8];
  const int* pad    = (const int*)d_in[9];
  const int* causal = (const int*)d_in[10];

  float* out   = (float*)d_out;                       // [B,S,D]
  float* alpha = out + (size_t)B_ * S_ * D_;          // [B,H,S,S]

  const size_t bhsd = (size_t)B_ * H_ * S_ * DK_;     // 4.19M floats
  float* Q  = (float*)d_ws;
  float* Kp = Q + bhsd;
  float* Vp = Kp + bhsd;
  float* Cw = Vp + bhsd;                              // context [B,S,D]

  dim3 blk(256);
  dim3 gproj(D_ / 128, (B_ * S_) / 128);              // (8, 32)
  k_proj<true><<<gproj, blk, 0, stream>>>(X, Wq, bq, Q,  B_ * S_, D_, D_);
  k_proj<true><<<gproj, blk, 0, stream>>>(X, Wk, bk, Kp, B_ * S_, D_, D_);
  k_proj<true><<<gproj, blk, 0, stream>>>(X, Wv, bv, Vp, B_ * S_, D_, D_);

  dim3 gsc(S_ / 128, S_ / 128, B_ * H_);              // (16,16,32)
  k_scores<<<gsc, blk, 0, stream>>>(Q, Kp, alpha, causal);

  k_softmax<<<dim3(B_ * H_ * S_), blk, 0, stream>>>(alpha, pad, causal);

  dim3 gpv(1, S_ / 64, B_ * H_);                      // (1,32,32)
  k_pv<<<gpv, blk, 0, stream>>>(alpha, Vp, Cw, causal);

  k_proj<false><<<gproj, blk, 0, stream>>>(Cw, Wo, bo, out, B_ * S_, D_, D_);
}

// Round 3
// 871.162 us; speedup vs baseline: 1.4084x; 1.4084x over previous
//
#include <hip/hip_runtime.h>
#include <cstdint>
#include <cstddef>

#define S_   2048
#define D_   1024
#define H_   16
#define DK_  64
#define BH_  32
#define M_   4096
#define NEG_INF_F (-3.4028234663852886e38f)

typedef short bf16x8 __attribute__((ext_vector_type(8)));
typedef float f32x4 __attribute__((ext_vector_type(4)));

__device__ __forceinline__ short f2b(float f) {
  union { float f; uint32_t u; } x; x.f = f;
  uint32_t r = (x.u + 0x7fffu + ((x.u >> 16) & 1u)) >> 16;  // RNE
  return (short)r;
}

// ---------------------------------------------------------------------------
// weights f32 -> bf16 (n4 = #float4 groups)
// ---------------------------------------------------------------------------
__global__ __launch_bounds__(256) void k_cvt(const float* __restrict__ in,
                                             short* __restrict__ out, int n4) {
  int i = blockIdx.x * 256 + threadIdx.x;
  if (i < n4) {
    float4 v = ((const float4*)in)[i];
    short4 s;
    s.x = f2b(v.x); s.y = f2b(v.y); s.z = f2b(v.z); s.w = f2b(v.w);
    ((short4*)out)[i] = s;
  }
}

// ---------------------------------------------------------------------------
// k_gemm: Y = A(f32)[M][K] @ W(bf16)[N][K]^T + bias.  MFMA 16x16x32 bf16.
// 128x128 tile, BK=32, 4 waves (2x2), 64x64 per wave (4x4 frags).
// MODE 0: write bf16 in [B,H,S,DK] head layout.  MODE 1: write f32 [M][N].
// ---------------------------------------------------------------------------
template <int MODE>
__global__ __launch_bounds__(256) void k_gemm(const float* __restrict__ A,
                                              const short* __restrict__ Wb,
                                              const float* __restrict__ bias,
                                              short* __restrict__ outb,
                                              float* __restrict__ outf) {
  __shared__ short As[128][40];   // [m][k], pad 40 (80B stride, 16B-aligned)
  __shared__ short Bs[128][40];   // [n][k]
  const int tid = threadIdx.x;
  const int m0 = blockIdx.y * 128, n0 = blockIdx.x * 128;
  const int wid = tid >> 6, lane = tid & 63;
  const int lr = lane & 15, lk8 = (lane >> 4) * 8;
  const int wm = (wid >> 1) * 64, wn = (wid & 1) * 64;

  f32x4 acc[4][4] = {};

  for (int kt = 0; kt < D_; kt += 32) {
#pragma unroll
    for (int i = 0; i < 4; ++i) {             // A: 128x32 f32 -> bf16
      int li = tid + i * 256;
      int r = li >> 3, c4 = li & 7;
      float4 v = *(const float4*)(A + (size_t)(m0 + r) * D_ + kt + c4 * 4);
      short4 s;
      s.x = f2b(v.x); s.y = f2b(v.y); s.z = f2b(v.z); s.w = f2b(v.w);
      *(short4*)&As[r][c4 * 4] = s;
    }
#pragma unroll
    for (int i = 0; i < 2; ++i) {             // B: 128x32 bf16, 4 int4/row
      int li = tid + i * 256;                 // 0..511
      int r = li >> 2, g = li & 3;            // r: 0..127, g: 0..3
      int4 w = *(const int4*)(Wb + (size_t)(n0 + r) * D_ + kt + g * 8);
      *(int4*)&Bs[r][g * 8] = w;
    }
    __syncthreads();

    bf16x8 af[4], bf[4];
#pragma unroll
    for (int x = 0; x < 4; ++x) {
      af[x] = *(const bf16x8*)&As[wm + x * 16 + lr][lk8];
      bf[x] = *(const bf16x8*)&Bs[wn + x * 16 + lr][lk8];
    }
#pragma unroll
    for (int mi = 0; mi < 4; ++mi)
#pragma unroll
      for (int ni = 0; ni < 4; ++ni)
        acc[mi][ni] = __builtin_amdgcn_mfma_f32_16x16x32_bf16(
            af[mi], bf[ni], acc[mi][ni], 0, 0, 0);
    __syncthreads();
  }

#pragma unroll
  for (int mi = 0; mi < 4; ++mi)
#pragma unroll
    for (int ni = 0; ni < 4; ++ni) {
      int n = n0 + wn + ni * 16 + lr;
      float bv = bias[n];
#pragma unroll
      for (int j = 0; j < 4; ++j) {
        int m = m0 + wm + mi * 16 + (lane >> 4) * 4 + j;
        float v = acc[mi][ni][j] + bv;
        if (MODE == 0) {
          int b = m >> 11, s = m & (S_ - 1);
          int h = n >> 6, dk = n & (DK_ - 1);
          outb[(((size_t)(b * H_ + h)) * S_ + s) * DK_ + dk] = f2b(v);
        } else {
          outf[(size_t)m * D_ + n] = v;
        }
      }
    }
}

// ---------------------------------------------------------------------------
// k_vt: V [BH][S][DK] bf16 -> VT [BH][DK][S] bf16 (64x64 LDS tiles)
// ---------------------------------------------------------------------------
__global__ __launch_bounds__(256) void k_vt(const short* __restrict__ V,
                                            short* __restrict__ VT) {
  __shared__ short t[64][72];
  const int tid = threadIdx.x;
  const int bh = blockIdx.y, s0 = blockIdx.x * 64;
  const short* src = V + ((size_t)bh * S_ + s0) * DK_;
#pragma unroll
  for (int i = 0; i < 2; ++i) {
    int li = tid + i * 256;
    int r = li >> 3, g = li & 7;
    int4 v = *(const int4*)(src + r * DK_ + g * 8);
    *(int4*)&t[r][g * 8] = v;
  }
  __syncthreads();
  short* dst = VT + (size_t)bh * DK_ * S_ + s0;
#pragma unroll
  for (int i = 0; i < 2; ++i) {
    int li = tid + i * 256;
    int dkr = li >> 3, g = li & 7;
    short o[8];
#pragma unroll
    for (int j = 0; j < 8; ++j) o[j] = t[g * 8 + j][dkr];
    *(int4*)(dst + (size_t)dkr * S_ + g * 8) = *(int4*)o;
  }
}

// ---------------------------------------------------------------------------
// k_ml: online-softmax stats per q row.  Per wave: 32 q rows, stream K in
// 16-col steps via MFMA (Q,K bf16 frags straight from global).  Writes
// m (row max) and 1/l (inv sum of exp) to workspace.
// ---------------------------------------------------------------------------
__global__ __launch_bounds__(256) void k_ml(const short* __restrict__ Q,
                                            const short* __restrict__ Kb,
                                            const int* __restrict__ pad,
                                            const int* __restrict__ causalp,
                                            float* __restrict__ mrow,
                                            float* __restrict__ lrow) {
  const int tid = threadIdx.x, wid = tid >> 6, lane = tid & 63;
  const int bh = blockIdx.y, q0 = blockIdx.x * 128, qw = q0 + wid * 32;
  const int lr = lane & 15, lk8 = (lane >> 4) * 8;
  const int b = bh >> 4;
  const short* Qb = Q + (size_t)bh * S_ * DK_;
  const short* Kp = Kb + (size_t)bh * S_ * DK_;

  bf16x8 qf[2][2];
#pragma unroll
  for (int qi = 0; qi < 2; ++qi)
#pragma unroll
    for (int h = 0; h < 2; ++h)
      qf[qi][h] = *(const bf16x8*)(Qb + (size_t)(qw + qi * 16 + lr) * DK_ +
                                   h * 32 + lk8);

  const int causal = *causalp;
  const int kend = causal ? (qw + 32) : S_;
  float m[8], l[8];
#pragma unroll
  for (int i = 0; i < 8; ++i) { m[i] = NEG_INF_F; l[i] = 0.f; }

  for (int kc = 0; kc < kend; kc += 16) {
    bf16x8 kf0 = *(const bf16x8*)(Kp + (size_t)(kc + lr) * DK_ + lk8);
    bf16x8 kf1 = *(const bf16x8*)(Kp + (size_t)(kc + lr) * DK_ + 32 + lk8);
    const int k = kc + lr;
    const bool kvalid = (pad[b * S_ + k] == 0);
    f32x4 sc[2];
#pragma unroll
    for (int qi = 0; qi < 2; ++qi) {
      f32x4 z = {0.f, 0.f, 0.f, 0.f};
      z = __builtin_amdgcn_mfma_f32_16x16x32_bf16(qf[qi][0], kf0, z, 0, 0, 0);
      z = __builtin_amdgcn_mfma_f32_16x16x32_bf16(qf[qi][1], kf1, z, 0, 0, 0);
      sc[qi] = z;
    }
#pragma unroll
    for (int qi = 0; qi < 2; ++qi)
#pragma unroll
      for (int j = 0; j < 4; ++j) {
        const int idx = qi * 4 + j;
        const int q = qw + qi * 16 + (lane >> 4) * 4 + j;
        float s = sc[qi][j] * 0.125f;
        if ((causal && k > q) || !kvalid) s = NEG_INF_F;
        float rmax = s;
#pragma unroll
        for (int off = 1; off < 16; off <<= 1)
          rmax = fmaxf(rmax, __shfl_xor(rmax, off));
        const float mn = fmaxf(m[idx], rmax);
        float e = __expf(s - mn);
#pragma unroll
        for (int off = 1; off < 16; off <<= 1) e += __shfl_xor(e, off);
        l[idx] = l[idx] * __expf(m[idx] - mn) + e;
        m[idx] = mn;
      }
  }

  if (lr == 0) {
#pragma unroll
    for (int qi = 0; qi < 2; ++qi)
#pragma unroll
      for (int j = 0; j < 4; ++j) {
        const int q = qw + qi * 16 + (lane >> 4) * 4 + j;
        mrow[bh * S_ + q] = m[qi * 4 + j];
        lrow[bh * S_ + q] = 1.0f / l[qi * 4 + j];
      }
  }
}

// ---------------------------------------------------------------------------
// k_apv: recompute scores, write final alpha (f32) once, accumulate PV via
// LDS-staged bf16 P tile and pre-transposed VT.  Context -> f32 [B,S,D].
// ---------------------------------------------------------------------------
__global__ __launch_bounds__(256) void k_apv(const short* __restrict__ Q,
                                             const short* __restrict__ Kb,
                                             const short* __restrict__ VT,
                                             const float* __restrict__ mrow,
                                             const float* __restrict__ lrow,
                                             const int* __restrict__ pad,
                                             const int* __restrict__ causalp,
                                             float* __restrict__ alpha,
                                             float* __restrict__ ctx) {
  __shared__ short P[4][32][40];   // per-wave P tile [q][k], pad 40
  const int tid = threadIdx.x, wid = tid >> 6, lane = tid & 63;
  const int bh = blockIdx.y, q0 = blockIdx.x * 128, qw = q0 + wid * 32;
  const int lr = lane & 15, lk8 = (lane >> 4) * 8;
  const int b = bh >> 4, hh = bh & (H_ - 1);
  const short* Qb = Q + (size_t)bh * S_ * DK_;
  const short* Kp = Kb + (size_t)bh * S_ * DK_;
  const short* VTb = VT + (size_t)bh * DK_ * S_;
  float* arow = alpha + (size_t)bh * S_ * S_;

  bf16x8 qf[2][2];
#pragma unroll
  for (int qi = 0; qi < 2; ++qi)
#pragma unroll
    for (int h = 0; h < 2; ++h)
      qf[qi][h] = *(const bf16x8*)(Qb + (size_t)(qw + qi * 16 + lr) * DK_ +
                                   h * 32 + lk8);

  float m8[8], li8[8];
#pragma unroll
  for (int qi = 0; qi < 2; ++qi)
#pragma unroll
    for (int j = 0; j < 4; ++j) {
      const int q = qw + qi * 16 + (lane >> 4) * 4 + j;
      m8[qi * 4 + j] = mrow[bh * S_ + q];
      li8[qi * 4 + j] = lrow[bh * S_ + q];
    }

  const int causal = *causalp;
  const int kend = causal ? (qw + 32) : S_;
  f32x4 cacc[2][4] = {};

  for (int kc = 0; kc < kend; kc += 32) {
#pragma unroll
    for (int h2 = 0; h2 < 2; ++h2) {
      const int kcc = kc + h2 * 16;
      bf16x8 kf0 = *(const bf16x8*)(Kp + (size_t)(kcc + lr) * DK_ + lk8);
      bf16x8 kf1 = *(const bf16x8*)(Kp + (size_t)(kcc + lr) * DK_ + 32 + lk8);
      const int k = kcc + lr;
      const bool kvalid = (pad[b * S_ + k] == 0);
#pragma unroll
      for (int qi = 0; qi < 2; ++qi) {
        f32x4 z = {0.f, 0.f, 0.f, 0.f};
        z = __builtin_amdgcn_mfma_f32_16x16x32_bf16(qf[qi][0], kf0, z, 0, 0, 0);
        z = __builtin_amdgcn_mfma_f32_16x16x32_bf16(qf[qi][1], kf1, z, 0, 0, 0);
#pragma unroll
        for (int j = 0; j < 4; ++j) {
          const int idx = qi * 4 + j;
          const int qrl = qi * 16 + (lane >> 4) * 4 + j;   // q within wave tile
          const int q = qw + qrl;
          float s = z[j] * 0.125f;
          if ((causal && k > q) || !kvalid) s = NEG_INF_F;
          const float a = __expf(s - m8[idx]) * li8[idx];
          arow[(size_t)q * S_ + k] = a;
          P[wid][qrl][h2 * 16 + lr] = f2b(a);
        }
      }
    }
    asm volatile("s_waitcnt lgkmcnt(0)" ::: "memory");
    __builtin_amdgcn_sched_barrier(0);

    bf16x8 pa[2];
    pa[0] = *(const bf16x8*)&P[wid][lr][lk8];
    pa[1] = *(const bf16x8*)&P[wid][16 + lr][lk8];
#pragma unroll
    for (int di = 0; di < 4; ++di) {
      bf16x8 vf = *(const bf16x8*)(VTb + (size_t)(di * 16 + lr) * S_ + kc + lk8);
      cacc[0][di] = __builtin_amdgcn_mfma_f32_16x16x32_bf16(pa[0], vf,
                                                            cacc[0][di], 0, 0, 0);
      cacc[1][di] = __builtin_amdgcn_mfma_f32_16x16x32_bf16(pa[1], vf,
                                                            cacc[1][di], 0, 0, 0);
    }
  }

  // zero-fill upper-triangular region of this wave's 32 rows
  if (causal) {
    const int kz = qw + 32;
    const int c4 = (S_ - kz) >> 2;
    for (int r = 0; r < 32; ++r) {
      float4* bp = (float4*)(arow + (size_t)(qw + r) * S_ + kz);
      for (int i = lane; i < c4; i += 64) bp[i] = make_float4(0.f, 0.f, 0.f, 0.f);
    }
  }

  // context write: f32 [B][S][D] (head-interleaved columns)
#pragma unroll
  for (int qi = 0; qi < 2; ++qi)
#pragma unroll
    for (int di = 0; di < 4; ++di)
#pragma unroll
      for (int j = 0; j < 4; ++j) {
        const int q = qw + qi * 16 + (lane >> 4) * 4 + j;
        const int dk = di * 16 + lr;
        ctx[((size_t)(b * S_ + q)) * D_ + hh * DK_ + dk] = cacc[qi][di][j];
      }
}

// ---------------------------------------------------------------------------
extern "C" void kernel_launch(void* const* d_in, const int* in_sizes, int n_in,
                              void* d_out, int out_size, void* d_ws,
                              size_t ws_size, hipStream_t stream) {
  (void)in_sizes; (void)n_in; (void)out_size; (void)ws_size;
  const float* X  = (const float*)d_in[0];
  const float* Wq = (const float*)d_in[1];
  const float* bq = (const float*)d_in[2];
  const float* Wk = (const float*)d_in[3];
  const float* bk = (const float*)d_in[4];
  const float* Wv = (const float*)d_in[5];
  const float* bv = (const float*)d_in[6];
  const float* Wo = (const float*)d_in[7];
  const float* bo = (const float*)d_in[8];
  const int* pad    = (const int*)d_in[9];
  const int* causal = (const int*)d_in[10];

  float* out   = (float*)d_out;                       // [B,S,D] f32
  float* alpha = out + (size_t)2 * S_ * D_;           // [B,H,S,S] f32

  short* wsb = (short*)d_ws;
  short* Wqb = wsb;
  short* Wkb = wsb + (size_t)(1 << 20);
  short* Wvb = wsb + (size_t)2 * (1 << 20);
  short* Wob = wsb + (size_t)3 * (1 << 20);
  short* Qb  = wsb + (size_t)4 * (1 << 20);           // 4M shorts each
  short* Kb  = wsb + (size_t)8 * (1 << 20);
  short* Vb  = wsb + (size_t)12 * (1 << 20);
  short* VTb = wsb + (size_t)16 * (1 << 20);
  float* mrow = (float*)(wsb + (size_t)20 * (1 << 20));
  float* lrow = mrow + (1 << 16);
  float* ctx  = lrow + (1 << 16);                     // 4M f32

  dim3 blk(256);

  // weights -> bf16
  k_cvt<<<dim3(1024), blk, 0, stream>>>(Wq, Wqb, (D_ * D_) / 4);
  k_cvt<<<dim3(1024), blk, 0, stream>>>(Wk, Wkb, (D_ * D_) / 4);
  k_cvt<<<dim3(1024), blk, 0, stream>>>(Wv, Wvb, (D_ * D_) / 4);
  k_cvt<<<dim3(1024), blk, 0, stream>>>(Wo, Wob, (D_ * D_) / 4);

  // QKV projections (MFMA), bf16 head-layout outputs
  dim3 gg(D_ / 128, M_ / 128);                        // (8, 32)
  k_gemm<0><<<gg, blk, 0, stream>>>(X, Wqb, bq, Qb, nullptr);
  k_gemm<0><<<gg, blk, 0, stream>>>(X, Wkb, bk, Kb, nullptr);
  k_gemm<0><<<gg, blk, 0, stream>>>(X, Wvb, bv, Vb, nullptr);

  // V -> V^T
  k_vt<<<dim3(S_ / 64, BH_), blk, 0, stream>>>(Vb, VTb);

  // online softmax stats
  dim3 ga(S_ / 128, BH_);                             // (16, 32)
  k_ml<<<ga, blk, 0, stream>>>(Qb, Kb, pad, causal, mrow, lrow);

  // alpha write + PV
  k_apv<<<ga, blk, 0, stream>>>(Qb, Kb, VTb, mrow, lrow, pad, causal,
                                alpha, ctx);

  // output projection (f32 out + bias)
  k_gemm<1><<<gg, blk, 0, stream>>>(ctx, Wob, bo, nullptr, out);
}

// Round 4
// 612.003 us; speedup vs baseline: 2.0048x; 1.4235x over previous
//
#include <hip/hip_runtime.h>
#include <cstdint>
#include <cstddef>

#define S_   2048
#define D_   1024
#define H_   16
#define DK_  64
#define BH_  32
#define M_   4096
#define NEG_INF_F (-3.4028234663852886e38f)

typedef short bf16x8 __attribute__((ext_vector_type(8)));
typedef float f32x4 __attribute__((ext_vector_type(4)));

__device__ __forceinline__ short f2b(float f) {
  union { float f; uint32_t u; } x; x.f = f;
  uint32_t r = (x.u + 0x7fffu + ((x.u >> 16) & 1u)) >> 16;  // RNE
  return (short)r;
}

// ---------------------------------------------------------------------------
// weights f32 -> bf16 (n4 = #float4 groups)
// ---------------------------------------------------------------------------
__global__ __launch_bounds__(256) void k_cvt(const float* __restrict__ in,
                                             short* __restrict__ out, int n4) {
  int i = blockIdx.x * 256 + threadIdx.x;
  if (i < n4) {
    float4 v = ((const float4*)in)[i];
    short4 s;
    s.x = f2b(v.x); s.y = f2b(v.y); s.z = f2b(v.z); s.w = f2b(v.w);
    ((short4*)out)[i] = s;
  }
}

// ---------------------------------------------------------------------------
// k_gemm: Y = (A(f32)[M][K] @ W(bf16)[N][K]^T + bias) * oscale.
// MFMA 16x16x32 bf16.  128x128 tile, BK=32, 4 waves (2x2), 64x64 per wave.
// MODE 0: write bf16 in [B,H,S,DK] head layout.  MODE 1: write f32 [M][N].
// ---------------------------------------------------------------------------
template <int MODE>
__global__ __launch_bounds__(256) void k_gemm(const float* __restrict__ A,
                                              const short* __restrict__ Wb,
                                              const float* __restrict__ bias,
                                              short* __restrict__ outb,
                                              float* __restrict__ outf,
                                              float oscale) {
  __shared__ short As[128][40];   // [m][k], pad 40 (80B stride, 16B-aligned)
  __shared__ short Bs[128][40];   // [n][k]
  const int tid = threadIdx.x;
  const int m0 = blockIdx.y * 128, n0 = blockIdx.x * 128;
  const int wid = tid >> 6, lane = tid & 63;
  const int lr = lane & 15, lk8 = (lane >> 4) * 8;
  const int wm = (wid >> 1) * 64, wn = (wid & 1) * 64;

  f32x4 acc[4][4] = {};

  for (int kt = 0; kt < D_; kt += 32) {
#pragma unroll
    for (int i = 0; i < 4; ++i) {             // A: 128x32 f32 -> bf16
      int li = tid + i * 256;
      int r = li >> 3, c4 = li & 7;
      float4 v = *(const float4*)(A + (size_t)(m0 + r) * D_ + kt + c4 * 4);
      short4 s;
      s.x = f2b(v.x); s.y = f2b(v.y); s.z = f2b(v.z); s.w = f2b(v.w);
      *(short4*)&As[r][c4 * 4] = s;
    }
#pragma unroll
    for (int i = 0; i < 2; ++i) {             // B: 128x32 bf16, 4 int4/row
      int li = tid + i * 256;                 // 0..511
      int r = li >> 2, g = li & 3;            // r: 0..127, g: 0..3
      int4 w = *(const int4*)(Wb + (size_t)(n0 + r) * D_ + kt + g * 8);
      *(int4*)&Bs[r][g * 8] = w;
    }
    __syncthreads();

    bf16x8 af[4], bf[4];
#pragma unroll
    for (int x = 0; x < 4; ++x) {
      af[x] = *(const bf16x8*)&As[wm + x * 16 + lr][lk8];
      bf[x] = *(const bf16x8*)&Bs[wn + x * 16 + lr][lk8];
    }
#pragma unroll
    for (int mi = 0; mi < 4; ++mi)
#pragma unroll
      for (int ni = 0; ni < 4; ++ni)
        acc[mi][ni] = __builtin_amdgcn_mfma_f32_16x16x32_bf16(
            af[mi], bf[ni], acc[mi][ni], 0, 0, 0);
    __syncthreads();
  }

#pragma unroll
  for (int mi = 0; mi < 4; ++mi)
#pragma unroll
    for (int ni = 0; ni < 4; ++ni) {
      int n = n0 + wn + ni * 16 + lr;
      float bv = bias[n];
#pragma unroll
      for (int j = 0; j < 4; ++j) {
        int m = m0 + wm + mi * 16 + (lane >> 4) * 4 + j;
        float v = (acc[mi][ni][j] + bv) * oscale;
        if (MODE == 0) {
          int b = m >> 11, s = m & (S_ - 1);
          int h = n >> 6, dk = n & (DK_ - 1);
          outb[(((size_t)(b * H_ + h)) * S_ + s) * DK_ + dk] = f2b(v);
        } else {
          outf[(size_t)m * D_ + n] = v;
        }
      }
    }
}

// ---------------------------------------------------------------------------
// k_vt: V [BH][S][DK] bf16 -> VT [BH][DK][S] bf16 (64x64 LDS tiles)
// ---------------------------------------------------------------------------
__global__ __launch_bounds__(256) void k_vt(const short* __restrict__ V,
                                            short* __restrict__ VT) {
  __shared__ short t[64][72];
  const int tid = threadIdx.x;
  const int bh = blockIdx.y, s0 = blockIdx.x * 64;
  const short* src = V + ((size_t)bh * S_ + s0) * DK_;
#pragma unroll
  for (int i = 0; i < 2; ++i) {
    int li = tid + i * 256;
    int r = li >> 3, g = li & 7;
    int4 v = *(const int4*)(src + r * DK_ + g * 8);
    *(int4*)&t[r][g * 8] = v;
  }
  __syncthreads();
  short* dst = VT + (size_t)bh * DK_ * S_ + s0;
#pragma unroll
  for (int i = 0; i < 2; ++i) {
    int li = tid + i * 256;
    int dkr = li >> 3, g = li & 7;
    short o[8];
#pragma unroll
    for (int j = 0; j < 8; ++j) o[j] = t[g * 8 + j][dkr];
    *(int4*)(dst + (size_t)dkr * S_ + g * 8) = *(int4*)o;
  }
}

// ---------------------------------------------------------------------------
// k_ml: online-softmax stats per q row.  Per-lane private (m,l) over the
// k-columns this lane sees (k = kc + lr); ONE cross-lane merge at the end.
// Q is pre-scaled by 1/sqrt(DK).  Writes m and 1/l per row.
// ---------------------------------------------------------------------------
__global__ __launch_bounds__(256) void k_ml(const short* __restrict__ Q,
                                            const short* __restrict__ Kb,
                                            const int* __restrict__ pad,
                                            const int* __restrict__ causalp,
                                            float* __restrict__ mrow,
                                            float* __restrict__ lrow) {
  const int tid = threadIdx.x, wid = tid >> 6, lane = tid & 63;
  const int bh = blockIdx.y, q0 = blockIdx.x * 128, qw = q0 + wid * 32;
  const int lr = lane & 15, lk8 = (lane >> 4) * 8;
  const int b = bh >> 4;
  const short* Qb = Q + (size_t)bh * S_ * DK_;
  const short* Kp = Kb + (size_t)bh * S_ * DK_;

  bf16x8 qf[2][2];
#pragma unroll
  for (int qi = 0; qi < 2; ++qi)
#pragma unroll
    for (int h = 0; h < 2; ++h)
      qf[qi][h] = *(const bf16x8*)(Qb + (size_t)(qw + qi * 16 + lr) * DK_ +
                                   h * 32 + lk8);

  const int causal = *causalp;
  const int kend = causal ? (qw + 32) : S_;
  float m[8], l[8];
#pragma unroll
  for (int i = 0; i < 8; ++i) { m[i] = -1e30f; l[i] = 0.f; }

  for (int kc = 0; kc < kend; kc += 32) {
#pragma unroll
    for (int h2 = 0; h2 < 2; ++h2) {
      const int kcc = kc + h2 * 16;
      bf16x8 kf0 = *(const bf16x8*)(Kp + (size_t)(kcc + lr) * DK_ + lk8);
      bf16x8 kf1 = *(const bf16x8*)(Kp + (size_t)(kcc + lr) * DK_ + 32 + lk8);
      const int k = kcc + lr;
      const bool kvalid = (pad[b * S_ + k] == 0);
#pragma unroll
      for (int qi = 0; qi < 2; ++qi) {
        f32x4 z = {0.f, 0.f, 0.f, 0.f};
        z = __builtin_amdgcn_mfma_f32_16x16x32_bf16(qf[qi][0], kf0, z, 0, 0, 0);
        z = __builtin_amdgcn_mfma_f32_16x16x32_bf16(qf[qi][1], kf1, z, 0, 0, 0);
#pragma unroll
        for (int j = 0; j < 4; ++j) {
          const int idx = qi * 4 + j;
          const int q = qw + qi * 16 + (lane >> 4) * 4 + j;
          float s = z[j];
          if ((causal && k > q) || !kvalid) s = NEG_INF_F;
          const float mn = fmaxf(m[idx], s);
          l[idx] = l[idx] * __expf(m[idx] - mn) + __expf(s - mn);
          m[idx] = mn;
        }
      }
    }
  }

  // merge (m,l) across the 16 lanes of each k-group (butterfly)
#pragma unroll
  for (int off = 1; off < 16; off <<= 1) {
#pragma unroll
    for (int idx = 0; idx < 8; ++idx) {
      const float mo = __shfl_xor(m[idx], off);
      const float lo = __shfl_xor(l[idx], off);
      const float mn = fmaxf(m[idx], mo);
      l[idx] = l[idx] * __expf(m[idx] - mn) + lo * __expf(mo - mn);
      m[idx] = mn;
    }
  }

  if (lr == 0) {
#pragma unroll
    for (int qi = 0; qi < 2; ++qi)
#pragma unroll
      for (int j = 0; j < 4; ++j) {
        const int q = qw + qi * 16 + (lane >> 4) * 4 + j;
        mrow[bh * S_ + q] = m[qi * 4 + j];
        lrow[bh * S_ + q] = 1.0f / l[qi * 4 + j];
      }
  }
}

// ---------------------------------------------------------------------------
// k_apv: recompute scores, write final alpha (f32) once, accumulate PV via
// LDS-staged bf16 P tile and pre-transposed VT.  Context -> f32 [B,S,D].
// ---------------------------------------------------------------------------
__global__ __launch_bounds__(256) void k_apv(const short* __restrict__ Q,
                                             const short* __restrict__ Kb,
                                             const short* __restrict__ VT,
                                             const float* __restrict__ mrow,
                                             const float* __restrict__ lrow,
                                             const int* __restrict__ pad,
                                             const int* __restrict__ causalp,
                                             float* __restrict__ alpha,
                                             float* __restrict__ ctx) {
  __shared__ short P[4][32][40];   // per-wave P tile [q][k], pad 40
  const int tid = threadIdx.x, wid = tid >> 6, lane = tid & 63;
  const int bh = blockIdx.y, q0 = blockIdx.x * 128, qw = q0 + wid * 32;
  const int lr = lane & 15, lk8 = (lane >> 4) * 8;
  const int b = bh >> 4, hh = bh & (H_ - 1);
  const short* Qb = Q + (size_t)bh * S_ * DK_;
  const short* Kp = Kb + (size_t)bh * S_ * DK_;
  const short* VTb = VT + (size_t)bh * DK_ * S_;
  float* arow = alpha + (size_t)bh * S_ * S_;

  bf16x8 qf[2][2];
#pragma unroll
  for (int qi = 0; qi < 2; ++qi)
#pragma unroll
    for (int h = 0; h < 2; ++h)
      qf[qi][h] = *(const bf16x8*)(Qb + (size_t)(qw + qi * 16 + lr) * DK_ +
                                   h * 32 + lk8);

  float m8[8], li8[8];
#pragma unroll
  for (int qi = 0; qi < 2; ++qi)
#pragma unroll
    for (int j = 0; j < 4; ++j) {
      const int q = qw + qi * 16 + (lane >> 4) * 4 + j;
      m8[qi * 4 + j] = mrow[bh * S_ + q];
      li8[qi * 4 + j] = lrow[bh * S_ + q];
    }

  const int causal = *causalp;
  const int kend = causal ? (qw + 32) : S_;
  f32x4 cacc[2][4] = {};

  for (int kc = 0; kc < kend; kc += 32) {
#pragma unroll
    for (int h2 = 0; h2 < 2; ++h2) {
      const int kcc = kc + h2 * 16;
      bf16x8 kf0 = *(const bf16x8*)(Kp + (size_t)(kcc + lr) * DK_ + lk8);
      bf16x8 kf1 = *(const bf16x8*)(Kp + (size_t)(kcc + lr) * DK_ + 32 + lk8);
      const int k = kcc + lr;
      const bool kvalid = (pad[b * S_ + k] == 0);
#pragma unroll
      for (int qi = 0; qi < 2; ++qi) {
        f32x4 z = {0.f, 0.f, 0.f, 0.f};
        z = __builtin_amdgcn_mfma_f32_16x16x32_bf16(qf[qi][0], kf0, z, 0, 0, 0);
        z = __builtin_amdgcn_mfma_f32_16x16x32_bf16(qf[qi][1], kf1, z, 0, 0, 0);
#pragma unroll
        for (int j = 0; j < 4; ++j) {
          const int idx = qi * 4 + j;
          const int qrl = qi * 16 + (lane >> 4) * 4 + j;   // q within wave tile
          const int q = qw + qrl;
          float s = z[j];
          if ((causal && k > q) || !kvalid) s = NEG_INF_F;
          const float a = __expf(s - m8[idx]) * li8[idx];
          arow[(size_t)q * S_ + k] = a;
          P[wid][qrl][h2 * 16 + lr] = f2b(a);
        }
      }
    }
    asm volatile("s_waitcnt lgkmcnt(0)" ::: "memory");
    __builtin_amdgcn_sched_barrier(0);

    bf16x8 pa[2];
    pa[0] = *(const bf16x8*)&P[wid][lr][lk8];
    pa[1] = *(const bf16x8*)&P[wid][16 + lr][lk8];
#pragma unroll
    for (int di = 0; di < 4; ++di) {
      bf16x8 vf = *(const bf16x8*)(VTb + (size_t)(di * 16 + lr) * S_ + kc + lk8);
      cacc[0][di] = __builtin_amdgcn_mfma_f32_16x16x32_bf16(pa[0], vf,
                                                            cacc[0][di], 0, 0, 0);
      cacc[1][di] = __builtin_amdgcn_mfma_f32_16x16x32_bf16(pa[1], vf,
                                                            cacc[1][di], 0, 0, 0);
    }
  }

  // zero-fill upper-triangular region of this wave's 32 rows
  if (causal) {
    const int kz = qw + 32;
    const int c4 = (S_ - kz) >> 2;
    for (int r = 0; r < 32; ++r) {
      float4* bp = (float4*)(arow + (size_t)(qw + r) * S_ + kz);
      for (int i = lane; i < c4; i += 64) bp[i] = make_float4(0.f, 0.f, 0.f, 0.f);
    }
  }

  // context write: f32 [B][S][D] (head-interleaved columns)
#pragma unroll
  for (int qi = 0; qi < 2; ++qi)
#pragma unroll
    for (int di = 0; di < 4; ++di)
#pragma unroll
      for (int j = 0; j < 4; ++j) {
        const int q = qw + qi * 16 + (lane >> 4) * 4 + j;
        const int dk = di * 16 + lr;
        ctx[((size_t)(b * S_ + q)) * D_ + hh * DK_ + dk] = cacc[qi][di][j];
      }
}

// ---------------------------------------------------------------------------
extern "C" void kernel_launch(void* const* d_in, const int* in_sizes, int n_in,
                              void* d_out, int out_size, void* d_ws,
                              size_t ws_size, hipStream_t stream) {
  (void)in_sizes; (void)n_in; (void)out_size; (void)ws_size;
  const float* X  = (const float*)d_in[0];
  const float* Wq = (const float*)d_in[1];
  const float* bq = (const float*)d_in[2];
  const float* Wk = (const float*)d_in[3];
  const float* bk = (const float*)d_in[4];
  const float* Wv = (const float*)d_in[5];
  const float* bv = (const float*)d_in[6];
  const float* Wo = (const float*)d_in[7];
  const float* bo = (const float*)d_in[8];
  const int* pad    = (const int*)d_in[9];
  const int* causal = (const int*)d_in[10];

  float* out   = (float*)d_out;                       // [B,S,D] f32
  float* alpha = out + (size_t)2 * S_ * D_;           // [B,H,S,S] f32

  short* wsb = (short*)d_ws;
  short* Wqb = wsb;
  short* Wkb = wsb + (size_t)(1 << 20);
  short* Wvb = wsb + (size_t)2 * (1 << 20);
  short* Wob = wsb + (size_t)3 * (1 << 20);
  short* Qb  = wsb + (size_t)4 * (1 << 20);           // 4M shorts each
  short* Kb  = wsb + (size_t)8 * (1 << 20);
  short* Vb  = wsb + (size_t)12 * (1 << 20);
  short* VTb = wsb + (size_t)16 * (1 << 20);
  float* mrow = (float*)(wsb + (size_t)20 * (1 << 20));
  float* lrow = mrow + (1 << 16);
  float* ctx  = lrow + (1 << 16);                     // 4M f32

  dim3 blk(256);

  // weights -> bf16
  k_cvt<<<dim3(1024), blk, 0, stream>>>(Wq, Wqb, (D_ * D_) / 4);
  k_cvt<<<dim3(1024), blk, 0, stream>>>(Wk, Wkb, (D_ * D_) / 4);
  k_cvt<<<dim3(1024), blk, 0, stream>>>(Wv, Wvb, (D_ * D_) / 4);
  k_cvt<<<dim3(1024), blk, 0, stream>>>(Wo, Wob, (D_ * D_) / 4);

  // QKV projections (MFMA); Q pre-scaled by 1/sqrt(DK) (2^-3, exact in bf16)
  dim3 gg(D_ / 128, M_ / 128);                        // (8, 32)
  k_gemm<0><<<gg, blk, 0, stream>>>(X, Wqb, bq, Qb, nullptr, 0.125f);
  k_gemm<0><<<gg, blk, 0, stream>>>(X, Wkb, bk, Kb, nullptr, 1.0f);
  k_gemm<0><<<gg, blk, 0, stream>>>(X, Wvb, bv, Vb, nullptr, 1.0f);

  // V -> V^T
  k_vt<<<dim3(S_ / 64, BH_), blk, 0, stream>>>(Vb, VTb);

  // online softmax stats
  dim3 ga(S_ / 128, BH_);                             // (16, 32)
  k_ml<<<ga, blk, 0, stream>>>(Qb, Kb, pad, causal, mrow, lrow);

  // alpha write + PV
  k_apv<<<ga, blk, 0, stream>>>(Qb, Kb, VTb, mrow, lrow, pad, causal,
                                alpha, ctx);

  // output projection (f32 out + bias)
  k_gemm<1><<<gg, blk, 0, stream>>>(ctx, Wob, bo, nullptr, out, 1.0f);
}

// Round 5
// 454.403 us; speedup vs baseline: 2.7002x; 1.3468x over previous
//
#include <hip/hip_runtime.h>
#include <cstdint>
#include <cstddef>

#define S_   2048
#define D_   1024
#define H_   16
#define DK_  64
#define BH_  32
#define M_   4096
#define NT_  64                      // 32-row q-tiles
#define NEG_INF_F (-3.4028234663852886e38f)

typedef short bf16x8 __attribute__((ext_vector_type(8)));
typedef float f32x4 __attribute__((ext_vector_type(4)));

__device__ __forceinline__ short f2b(float f) {
  union { float f; uint32_t u; } x; x.f = f;
  uint32_t r = (x.u + 0x7fffu + ((x.u >> 16) & 1u)) >> 16;  // RNE
  return (short)r;
}

// ---------------------------------------------------------------------------
// k_cvt5: f32 -> bf16 for X (job 0) and the 4 weight matrices (jobs 1..4).
// ---------------------------------------------------------------------------
__global__ __launch_bounds__(256) void k_cvt5(
    const float* __restrict__ X,  const float* __restrict__ Wq,
    const float* __restrict__ Wk, const float* __restrict__ Wv,
    const float* __restrict__ Wo,
    short* __restrict__ Xb,  short* __restrict__ Wqb,
    short* __restrict__ Wkb, short* __restrict__ Wvb,
    short* __restrict__ Wob) {
  const int job = blockIdx.y;
  const float* src = job == 0 ? X : job == 1 ? Wq : job == 2 ? Wk
                   : job == 3 ? Wv : Wo;
  short* dst = job == 0 ? Xb : job == 1 ? Wqb : job == 2 ? Wkb
             : job == 3 ? Wvb : Wob;
  const int n4 = (job == 0) ? (M_ * D_ / 4) : (D_ * D_ / 4);
  const int i = blockIdx.x * 256 + threadIdx.x;
  if (i < n4) {
    float4 v = ((const float4*)src)[i];
    short4 s;
    s.x = f2b(v.x); s.y = f2b(v.y); s.z = f2b(v.z); s.w = f2b(v.w);
    ((short4*)dst)[i] = s;
  }
}

// ---------------------------------------------------------------------------
// k_qkv: fused QKV projection.  A = Xb bf16 [M][K]; z selects W/bias/dst.
// Y = (A @ W^T + bias) * (z==0 ? 1/8 : 1), bf16 head layout [B,H,S,DK].
// 128x128 tile, BK=32, 4 waves (2x2), MFMA 16x16x32 bf16.
// ---------------------------------------------------------------------------
__global__ __launch_bounds__(256) void k_qkv(
    const short* __restrict__ Ab,
    const short* __restrict__ W0, const short* __restrict__ W1,
    const short* __restrict__ W2,
    const float* __restrict__ b0, const float* __restrict__ b1,
    const float* __restrict__ b2,
    short* __restrict__ o0, short* __restrict__ o1, short* __restrict__ o2) {
  __shared__ short As[128][40];
  __shared__ short Bs[128][40];
  const int z = blockIdx.z;
  const short* Wb = z == 0 ? W0 : z == 1 ? W1 : W2;
  const float* bias = z == 0 ? b0 : z == 1 ? b1 : b2;
  short* outb = z == 0 ? o0 : z == 1 ? o1 : o2;
  const float oscale = (z == 0) ? 0.125f : 1.0f;

  const int tid = threadIdx.x;
  const int m0 = blockIdx.y * 128, n0 = blockIdx.x * 128;
  const int wid = tid >> 6, lane = tid & 63;
  const int lr = lane & 15, lk8 = (lane >> 4) * 8;
  const int wm = (wid >> 1) * 64, wn = (wid & 1) * 64;

  f32x4 acc[4][4] = {};

  for (int kt = 0; kt < D_; kt += 32) {
#pragma unroll
    for (int i = 0; i < 2; ++i) {
      int li = tid + i * 256;
      int r = li >> 2, g = li & 3;
      int4 a = *(const int4*)(Ab + (size_t)(m0 + r) * D_ + kt + g * 8);
      *(int4*)&As[r][g * 8] = a;
      int4 w = *(const int4*)(Wb + (size_t)(n0 + r) * D_ + kt + g * 8);
      *(int4*)&Bs[r][g * 8] = w;
    }
    __syncthreads();

    bf16x8 af[4], bf[4];
#pragma unroll
    for (int x = 0; x < 4; ++x) {
      af[x] = *(const bf16x8*)&As[wm + x * 16 + lr][lk8];
      bf[x] = *(const bf16x8*)&Bs[wn + x * 16 + lr][lk8];
    }
#pragma unroll
    for (int mi = 0; mi < 4; ++mi)
#pragma unroll
      for (int ni = 0; ni < 4; ++ni)
        acc[mi][ni] = __builtin_amdgcn_mfma_f32_16x16x32_bf16(
            af[mi], bf[ni], acc[mi][ni], 0, 0, 0);
    __syncthreads();
  }

#pragma unroll
  for (int mi = 0; mi < 4; ++mi)
#pragma unroll
    for (int ni = 0; ni < 4; ++ni) {
      int n = n0 + wn + ni * 16 + lr;
      float bv = bias[n];
#pragma unroll
      for (int j = 0; j < 4; ++j) {
        int m = m0 + wm + mi * 16 + (lane >> 4) * 4 + j;
        float v = (acc[mi][ni][j] + bv) * oscale;
        int b = m >> 11, s = m & (S_ - 1);
        int h = n >> 6, dk = n & (DK_ - 1);
        outb[(((size_t)(b * H_ + h)) * S_ + s) * DK_ + dk] = f2b(v);
      }
    }
}

// ---------------------------------------------------------------------------
// k_vt: V [BH][S][DK] bf16 -> VT [BH][DK][S] bf16 (64x64 LDS tiles)
// ---------------------------------------------------------------------------
__global__ __launch_bounds__(256) void k_vt(const short* __restrict__ V,
                                            short* __restrict__ VT) {
  __shared__ short t[64][72];
  const int tid = threadIdx.x;
  const int bh = blockIdx.y, s0 = blockIdx.x * 64;
  const short* src = V + ((size_t)bh * S_ + s0) * DK_;
#pragma unroll
  for (int i = 0; i < 2; ++i) {
    int li = tid + i * 256;
    int r = li >> 3, g = li & 7;
    int4 v = *(const int4*)(src + r * DK_ + g * 8);
    *(int4*)&t[r][g * 8] = v;
  }
  __syncthreads();
  short* dst = VT + (size_t)bh * DK_ * S_ + s0;
#pragma unroll
  for (int i = 0; i < 2; ++i) {
    int li = tid + i * 256;
    int dkr = li >> 3, g = li & 7;
    short o[8];
#pragma unroll
    for (int j = 0; j < 8; ++j) o[j] = t[g * 8 + j][dkr];
    *(int4*)(dst + (size_t)dkr * S_ + g * 8) = *(int4*)o;
  }
}

// ---------------------------------------------------------------------------
// k_apv: merged stats + alpha + PV.  One wave (64 thr) per 32-row q-tile.
// Pass 1: per-lane online (m,l) over k columns, one 4-step butterfly merge.
// Pass 2: recompute scores, alpha staged in LDS (XOR-swizzled) -> float4
// coalesced writes; P bf16 tile -> PV MFMA with pre-transposed VT.
// ctx written bf16 head-interleaved [B][S][D].
// ---------------------------------------------------------------------------
__global__ __launch_bounds__(64) void k_apv(const short* __restrict__ Q,
                                            const short* __restrict__ Kb,
                                            const short* __restrict__ VT,
                                            const int* __restrict__ pad,
                                            const int* __restrict__ causalp,
                                            float* __restrict__ alpha,
                                            short* __restrict__ ctxb) {
  __shared__ short P[32][40];      // bf16 P tile [q][k]
  __shared__ float Af[32][32];     // f32 alpha tile, chunk-XOR swizzled
  const int lane = threadIdx.x;
  const int bh = blockIdx.y;
  const int tile = (NT_ - 1) - blockIdx.x;   // big tiles dispatch first
  const int qw = tile * 32;
  const int lr = lane & 15, lk8 = (lane >> 4) * 8;
  const int g4 = (lane >> 4) * 4;
  const int b = bh >> 4, hh = bh & (H_ - 1);
  const short* Qb = Q + (size_t)bh * S_ * DK_;
  const short* Kp = Kb + (size_t)bh * S_ * DK_;
  const short* VTb = VT + (size_t)bh * DK_ * S_;
  float* arow = alpha + (size_t)bh * S_ * S_;

  bf16x8 qf[2][2];
#pragma unroll
  for (int qi = 0; qi < 2; ++qi)
#pragma unroll
    for (int h = 0; h < 2; ++h)
      qf[qi][h] = *(const bf16x8*)(Qb + (size_t)(qw + qi * 16 + lr) * DK_ +
                                   h * 32 + lk8);

  const int causal = *causalp;
  const int kend = causal ? (qw + 32) : S_;

  // ---- pass 1: online (m,l), per-lane private, merge once ----
  float m[8], l[8];
#pragma unroll
  for (int i = 0; i < 8; ++i) { m[i] = -1e30f; l[i] = 0.f; }

  for (int kc = 0; kc < kend; kc += 32) {
#pragma unroll
    for (int h2 = 0; h2 < 2; ++h2) {
      const int kcc = kc + h2 * 16;
      bf16x8 kf0 = *(const bf16x8*)(Kp + (size_t)(kcc + lr) * DK_ + lk8);
      bf16x8 kf1 = *(const bf16x8*)(Kp + (size_t)(kcc + lr) * DK_ + 32 + lk8);
      const int k = kcc + lr;
      const bool kvalid = (pad[b * S_ + k] == 0);
#pragma unroll
      for (int qi = 0; qi < 2; ++qi) {
        f32x4 z = {0.f, 0.f, 0.f, 0.f};
        z = __builtin_amdgcn_mfma_f32_16x16x32_bf16(qf[qi][0], kf0, z, 0, 0, 0);
        z = __builtin_amdgcn_mfma_f32_16x16x32_bf16(qf[qi][1], kf1, z, 0, 0, 0);
#pragma unroll
        for (int j = 0; j < 4; ++j) {
          const int idx = qi * 4 + j;
          const int q = qw + qi * 16 + g4 + j;
          float s = z[j];
          if ((causal && k > q) || !kvalid) s = NEG_INF_F;
          const float mn = fmaxf(m[idx], s);
          l[idx] = l[idx] * __expf(m[idx] - mn) + __expf(s - mn);
          m[idx] = mn;
        }
      }
    }
  }
#pragma unroll
  for (int off = 1; off < 16; off <<= 1) {
#pragma unroll
    for (int idx = 0; idx < 8; ++idx) {
      const float mo = __shfl_xor(m[idx], off);
      const float lo = __shfl_xor(l[idx], off);
      const float mn = fmaxf(m[idx], mo);
      l[idx] = l[idx] * __expf(m[idx] - mn) + lo * __expf(mo - mn);
      m[idx] = mn;
    }
  }
  float li8[8];
#pragma unroll
  for (int i = 0; i < 8; ++i) li8[i] = 1.0f / l[i];

  // ---- pass 2: alpha + PV ----
  f32x4 cacc[2][4] = {};

  for (int kc = 0; kc < kend; kc += 32) {
#pragma unroll
    for (int h2 = 0; h2 < 2; ++h2) {
      const int kcc = kc + h2 * 16;
      bf16x8 kf0 = *(const bf16x8*)(Kp + (size_t)(kcc + lr) * DK_ + lk8);
      bf16x8 kf1 = *(const bf16x8*)(Kp + (size_t)(kcc + lr) * DK_ + 32 + lk8);
      const int k = kcc + lr;
      const bool kvalid = (pad[b * S_ + k] == 0);
#pragma unroll
      for (int qi = 0; qi < 2; ++qi) {
        f32x4 z = {0.f, 0.f, 0.f, 0.f};
        z = __builtin_amdgcn_mfma_f32_16x16x32_bf16(qf[qi][0], kf0, z, 0, 0, 0);
        z = __builtin_amdgcn_mfma_f32_16x16x32_bf16(qf[qi][1], kf1, z, 0, 0, 0);
#pragma unroll
        for (int j = 0; j < 4; ++j) {
          const int idx = qi * 4 + j;
          const int qrl = qi * 16 + g4 + j;
          const int q = qw + qrl;
          float s = z[j];
          if ((causal && k > q) || !kvalid) s = NEG_INF_F;
          const float a = __expf(s - m[idx]) * li8[idx];
          P[qrl][h2 * 16 + lr] = f2b(a);
          const int v = h2 * 16 + lr;
          const int cp = (v >> 2) ^ (qrl & 7);      // chunk XOR swizzle
          Af[qrl][cp * 4 + (v & 3)] = a;
        }
      }
    }
    asm volatile("s_waitcnt lgkmcnt(0)" ::: "memory");
    __builtin_amdgcn_sched_barrier(0);

    // coalesced alpha write: 32 rows x 128B
#pragma unroll
    for (int p = 0; p < 4; ++p) {
      const int row = p * 8 + (lane >> 3);
      const int c = lane & 7;
      float4 w = *(const float4*)&Af[row][((c ^ (row & 7)) << 2)];
      *(float4*)(arow + (size_t)(qw + row) * S_ + kc + c * 4) = w;
    }

    // PV
    bf16x8 pa[2];
    pa[0] = *(const bf16x8*)&P[lr][lk8];
    pa[1] = *(const bf16x8*)&P[16 + lr][lk8];
#pragma unroll
    for (int di = 0; di < 4; ++di) {
      bf16x8 vf = *(const bf16x8*)(VTb + (size_t)(di * 16 + lr) * S_ + kc + lk8);
      cacc[0][di] = __builtin_amdgcn_mfma_f32_16x16x32_bf16(pa[0], vf,
                                                            cacc[0][di], 0, 0, 0);
      cacc[1][di] = __builtin_amdgcn_mfma_f32_16x16x32_bf16(pa[1], vf,
                                                            cacc[1][di], 0, 0, 0);
    }
  }

  // zero-fill upper-triangular region of this tile's 32 rows
  if (causal) {
    const int kz = qw + 32;
    const int c4 = (S_ - kz) >> 2;
    for (int r = 0; r < 32; ++r) {
      float4* bp = (float4*)(arow + (size_t)(qw + r) * S_ + kz);
      for (int i = lane; i < c4; i += 64) bp[i] = make_float4(0.f, 0.f, 0.f, 0.f);
    }
  }

  // ctx write: bf16 [B][S][D] head-interleaved
#pragma unroll
  for (int qi = 0; qi < 2; ++qi)
#pragma unroll
    for (int di = 0; di < 4; ++di)
#pragma unroll
      for (int j = 0; j < 4; ++j) {
        const int q = qw + qi * 16 + g4 + j;
        const int dk = di * 16 + lr;
        ctxb[((size_t)(b * S_ + q)) * D_ + hh * DK_ + dk] = f2b(cacc[qi][di][j]);
      }
}

// ---------------------------------------------------------------------------
// k_oproj: out = ctxb(bf16) @ Wo^T + bo, f32 [M][D].
// ---------------------------------------------------------------------------
__global__ __launch_bounds__(256) void k_oproj(const short* __restrict__ Ab,
                                               const short* __restrict__ Wb,
                                               const float* __restrict__ bias,
                                               float* __restrict__ outf) {
  __shared__ short As[128][40];
  __shared__ short Bs[128][40];
  const int tid = threadIdx.x;
  const int m0 = blockIdx.y * 128, n0 = blockIdx.x * 128;
  const int wid = tid >> 6, lane = tid & 63;
  const int lr = lane & 15, lk8 = (lane >> 4) * 8;
  const int wm = (wid >> 1) * 64, wn = (wid & 1) * 64;

  f32x4 acc[4][4] = {};

  for (int kt = 0; kt < D_; kt += 32) {
#pragma unroll
    for (int i = 0; i < 2; ++i) {
      int li = tid + i * 256;
      int r = li >> 2, g = li & 3;
      int4 a = *(const int4*)(Ab + (size_t)(m0 + r) * D_ + kt + g * 8);
      *(int4*)&As[r][g * 8] = a;
      int4 w = *(const int4*)(Wb + (size_t)(n0 + r) * D_ + kt + g * 8);
      *(int4*)&Bs[r][g * 8] = w;
    }
    __syncthreads();

    bf16x8 af[4], bf[4];
#pragma unroll
    for (int x = 0; x < 4; ++x) {
      af[x] = *(const bf16x8*)&As[wm + x * 16 + lr][lk8];
      bf[x] = *(const bf16x8*)&Bs[wn + x * 16 + lr][lk8];
    }
#pragma unroll
    for (int mi = 0; mi < 4; ++mi)
#pragma unroll
      for (int ni = 0; ni < 4; ++ni)
        acc[mi][ni] = __builtin_amdgcn_mfma_f32_16x16x32_bf16(
            af[mi], bf[ni], acc[mi][ni], 0, 0, 0);
    __syncthreads();
  }

#pragma unroll
  for (int mi = 0; mi < 4; ++mi)
#pragma unroll
    for (int ni = 0; ni < 4; ++ni) {
      int n = n0 + wn + ni * 16 + lr;
      float bv = bias[n];
#pragma unroll
      for (int j = 0; j < 4; ++j) {
        int mm = m0 + wm + mi * 16 + (lane >> 4) * 4 + j;
        outf[(size_t)mm * D_ + n] = acc[mi][ni][j] + bv;
      }
    }
}

// ---------------------------------------------------------------------------
extern "C" void kernel_launch(void* const* d_in, const int* in_sizes, int n_in,
                              void* d_out, int out_size, void* d_ws,
                              size_t ws_size, hipStream_t stream) {
  (void)in_sizes; (void)n_in; (void)out_size; (void)ws_size;
  const float* X  = (const float*)d_in[0];
  const float* Wq = (const float*)d_in[1];
  const float* bq = (const float*)d_in[2];
  const float* Wk = (const float*)d_in[3];
  const float* bk = (const float*)d_in[4];
  const float* Wv = (const float*)d_in[5];
  const float* bv = (const float*)d_in[6];
  const float* Wo = (const float*)d_in[7];
  const float* bo = (const float*)d_in[8];
  const int* pad    = (const int*)d_in[9];
  const int* causal = (const int*)d_in[10];

  float* out   = (float*)d_out;                       // [B,S,D] f32
  float* alpha = out + (size_t)2 * S_ * D_;           // [B,H,S,S] f32

  short* wsb = (short*)d_ws;
  const size_t MM = (size_t)1 << 20;                  // 1M shorts
  short* Xb   = wsb;                                  // 4M
  short* Wqb  = wsb + 4 * MM;                         // 1M
  short* Wkb  = wsb + 5 * MM;
  short* Wvb  = wsb + 6 * MM;
  short* Wob  = wsb + 7 * MM;
  short* Qb   = wsb + 8 * MM;                         // 4M each
  short* Kb   = wsb + 12 * MM;
  short* Vb   = wsb + 16 * MM;
  short* VTb  = wsb + 20 * MM;
  short* ctxb = wsb + 24 * MM;                        // 4M

  dim3 blk(256);

  // X + weights -> bf16
  k_cvt5<<<dim3(4096, 5), blk, 0, stream>>>(X, Wq, Wk, Wv, Wo,
                                            Xb, Wqb, Wkb, Wvb, Wob);

  // fused QKV projection (Q pre-scaled by 1/8)
  k_qkv<<<dim3(D_ / 128, M_ / 128, 3), blk, 0, stream>>>(
      Xb, Wqb, Wkb, Wvb, bq, bk, bv, Qb, Kb, Vb);

  // V -> V^T
  k_vt<<<dim3(S_ / 64, BH_), blk, 0, stream>>>(Vb, VTb);

  // merged stats + alpha + PV (one wave per 32-row q-tile)
  k_apv<<<dim3(NT_, BH_), dim3(64), 0, stream>>>(Qb, Kb, VTb, pad, causal,
                                                 alpha, ctxb);

  // output projection
  k_oproj<<<dim3(D_ / 128, M_ / 128), blk, 0, stream>>>(ctxb, Wob, bo, out);
}

// Round 6
// 359.371 us; speedup vs baseline: 3.4142x; 1.2644x over previous
//
#include <hip/hip_runtime.h>
#include <cstdint>
#include <cstddef>

#define S_   2048
#define D_   1024
#define H_   16
#define DK_  64
#define BH_  32
#define M_   4096
#define NT_  64                      // 32-row q-tiles
#define NEG_INF_F (-3.4028234663852886e38f)

typedef short bf16x8 __attribute__((ext_vector_type(8)));
typedef float f32x4 __attribute__((ext_vector_type(4)));

__device__ __forceinline__ short f2b(float f) {
  union { float f; uint32_t u; } x; x.f = f;
  uint32_t r = (x.u + 0x7fffu + ((x.u >> 16) & 1u)) >> 16;  // RNE
  return (short)r;
}

// ---------------------------------------------------------------------------
// k_cvt5: f32 -> bf16 for X (job 0) and the 4 weight matrices (jobs 1..4).
// ---------------------------------------------------------------------------
__global__ __launch_bounds__(256) void k_cvt5(
    const float* __restrict__ X,  const float* __restrict__ Wq,
    const float* __restrict__ Wk, const float* __restrict__ Wv,
    const float* __restrict__ Wo,
    short* __restrict__ Xb,  short* __restrict__ Wqb,
    short* __restrict__ Wkb, short* __restrict__ Wvb,
    short* __restrict__ Wob) {
  const int job = blockIdx.y;
  const float* src = job == 0 ? X : job == 1 ? Wq : job == 2 ? Wk
                   : job == 3 ? Wv : Wo;
  short* dst = job == 0 ? Xb : job == 1 ? Wqb : job == 2 ? Wkb
             : job == 3 ? Wvb : Wob;
  const int n4 = (job == 0) ? (M_ * D_ / 4) : (D_ * D_ / 4);
  const int i = blockIdx.x * 256 + threadIdx.x;
  if (i < n4) {
    float4 v = ((const float4*)src)[i];
    short4 s;
    s.x = f2b(v.x); s.y = f2b(v.y); s.z = f2b(v.z); s.w = f2b(v.w);
    ((short4*)dst)[i] = s;
  }
}

// ---------------------------------------------------------------------------
// k_qkv: fused QKV projection.  A = Xb bf16 [M][K]; z selects W/bias/dst.
// Y = (A @ W^T + bias) * (z==0 ? 1/8 : 1), bf16 head layout [B,H,S,DK].
// ---------------------------------------------------------------------------
__global__ __launch_bounds__(256) void k_qkv(
    const short* __restrict__ Ab,
    const short* __restrict__ W0, const short* __restrict__ W1,
    const short* __restrict__ W2,
    const float* __restrict__ b0, const float* __restrict__ b1,
    const float* __restrict__ b2,
    short* __restrict__ o0, short* __restrict__ o1, short* __restrict__ o2) {
  __shared__ short As[128][40];
  __shared__ short Bs[128][40];
  const int z = blockIdx.z;
  const short* Wb = z == 0 ? W0 : z == 1 ? W1 : W2;
  const float* bias = z == 0 ? b0 : z == 1 ? b1 : b2;
  short* outb = z == 0 ? o0 : z == 1 ? o1 : o2;
  const float oscale = (z == 0) ? 0.125f : 1.0f;

  const int tid = threadIdx.x;
  const int m0 = blockIdx.y * 128, n0 = blockIdx.x * 128;
  const int wid = tid >> 6, lane = tid & 63;
  const int lr = lane & 15, lk8 = (lane >> 4) * 8;
  const int wm = (wid >> 1) * 64, wn = (wid & 1) * 64;

  f32x4 acc[4][4] = {};

  for (int kt = 0; kt < D_; kt += 32) {
#pragma unroll
    for (int i = 0; i < 2; ++i) {
      int li = tid + i * 256;
      int r = li >> 2, g = li & 3;
      int4 a = *(const int4*)(Ab + (size_t)(m0 + r) * D_ + kt + g * 8);
      *(int4*)&As[r][g * 8] = a;
      int4 w = *(const int4*)(Wb + (size_t)(n0 + r) * D_ + kt + g * 8);
      *(int4*)&Bs[r][g * 8] = w;
    }
    __syncthreads();

    bf16x8 af[4], bf[4];
#pragma unroll
    for (int x = 0; x < 4; ++x) {
      af[x] = *(const bf16x8*)&As[wm + x * 16 + lr][lk8];
      bf[x] = *(const bf16x8*)&Bs[wn + x * 16 + lr][lk8];
    }
#pragma unroll
    for (int mi = 0; mi < 4; ++mi)
#pragma unroll
      for (int ni = 0; ni < 4; ++ni)
        acc[mi][ni] = __builtin_amdgcn_mfma_f32_16x16x32_bf16(
            af[mi], bf[ni], acc[mi][ni], 0, 0, 0);
    __syncthreads();
  }

#pragma unroll
  for (int mi = 0; mi < 4; ++mi)
#pragma unroll
    for (int ni = 0; ni < 4; ++ni) {
      int n = n0 + wn + ni * 16 + lr;
      float bv = bias[n];
#pragma unroll
      for (int j = 0; j < 4; ++j) {
        int m = m0 + wm + mi * 16 + (lane >> 4) * 4 + j;
        float v = (acc[mi][ni][j] + bv) * oscale;
        int b = m >> 11, s = m & (S_ - 1);
        int h = n >> 6, dk = n & (DK_ - 1);
        outb[(((size_t)(b * H_ + h)) * S_ + s) * DK_ + dk] = f2b(v);
      }
    }
}

// ---------------------------------------------------------------------------
// k_vt: V [BH][S][DK] bf16 -> VT [BH][DK][S] bf16 (64x64 LDS tiles)
// ---------------------------------------------------------------------------
__global__ __launch_bounds__(256) void k_vt(const short* __restrict__ V,
                                            short* __restrict__ VT) {
  __shared__ short t[64][72];
  const int tid = threadIdx.x;
  const int bh = blockIdx.y, s0 = blockIdx.x * 64;
  const short* src = V + ((size_t)bh * S_ + s0) * DK_;
#pragma unroll
  for (int i = 0; i < 2; ++i) {
    int li = tid + i * 256;
    int r = li >> 3, g = li & 7;
    int4 v = *(const int4*)(src + r * DK_ + g * 8);
    *(int4*)&t[r][g * 8] = v;
  }
  __syncthreads();
  short* dst = VT + (size_t)bh * DK_ * S_ + s0;
#pragma unroll
  for (int i = 0; i < 2; ++i) {
    int li = tid + i * 256;
    int dkr = li >> 3, g = li & 7;
    short o[8];
#pragma unroll
    for (int j = 0; j < 8; ++j) o[j] = t[g * 8 + j][dkr];
    *(int4*)(dst + (size_t)dkr * S_ + g * 8) = *(int4*)o;
  }
}

// ---------------------------------------------------------------------------
// k_apv: merged stats + alpha + PV.  4 waves per 32-row q-tile; waves split
// the K range (wave w takes steps w, w+4, ...).  Pass 1: per-wave (m,l),
// lane butterfly, cross-wave LDS merge.  Pass 2: per-wave alpha chunks
// (LDS-staged float4 writes) + partial PV; PV partials reduced via LDS
// aliased onto the dead P/Af region.  ctx written bf16 [B][S][D].
// ---------------------------------------------------------------------------
__global__ __launch_bounds__(256) void k_apv(const short* __restrict__ Q,
                                             const short* __restrict__ Kb,
                                             const short* __restrict__ VT,
                                             const int* __restrict__ pad,
                                             const int* __restrict__ causalp,
                                             float* __restrict__ alpha,
                                             short* __restrict__ ctxb) {
  __shared__ __align__(16) char smem_u[26624];   // P[4][32][40]s + Af[4][32][32]f
  __shared__ float ml[4][32][2];                 // cross-wave (m,l)
  short (*P)[32][40]  = (short(*)[32][40])smem_u;
  float (*Af)[32][32] = (float(*)[32][32])(smem_u + 10240);
  float (*red)[64][32] = (float(*)[64][32])smem_u;   // [3][64][32], aliased

  const int tid = threadIdx.x, wid = tid >> 6, lane = tid & 63;
  const int bh = blockIdx.y;
  const int tile = (NT_ - 1) - blockIdx.x;   // big tiles dispatch first
  const int qw = tile * 32;
  const int lr = lane & 15, lk8 = (lane >> 4) * 8;
  const int g4 = (lane >> 4) * 4;
  const int b = bh >> 4, hh = bh & (H_ - 1);
  const short* Qb = Q + (size_t)bh * S_ * DK_;
  const short* Kp = Kb + (size_t)bh * S_ * DK_;
  const short* VTb = VT + (size_t)bh * DK_ * S_;
  float* arow = alpha + (size_t)bh * S_ * S_;

  bf16x8 qf[2][2];
#pragma unroll
  for (int qi = 0; qi < 2; ++qi)
#pragma unroll
    for (int h = 0; h < 2; ++h)
      qf[qi][h] = *(const bf16x8*)(Qb + (size_t)(qw + qi * 16 + lr) * DK_ +
                                   h * 32 + lk8);

  const int causal = *causalp;
  const int nsteps = causal ? (tile + 1) : (S_ / 32);

  // ---- pass 1: per-wave online (m,l) over strided k-steps ----
  float m[8], l[8];
#pragma unroll
  for (int i = 0; i < 8; ++i) { m[i] = -1e30f; l[i] = 0.f; }

  for (int st = wid; st < nsteps; st += 4) {
    const int kc = st * 32;
#pragma unroll
    for (int h2 = 0; h2 < 2; ++h2) {
      const int kcc = kc + h2 * 16;
      bf16x8 kf0 = *(const bf16x8*)(Kp + (size_t)(kcc + lr) * DK_ + lk8);
      bf16x8 kf1 = *(const bf16x8*)(Kp + (size_t)(kcc + lr) * DK_ + 32 + lk8);
      const int k = kcc + lr;
      const bool kvalid = (pad[b * S_ + k] == 0);
#pragma unroll
      for (int qi = 0; qi < 2; ++qi) {
        f32x4 z = {0.f, 0.f, 0.f, 0.f};
        z = __builtin_amdgcn_mfma_f32_16x16x32_bf16(qf[qi][0], kf0, z, 0, 0, 0);
        z = __builtin_amdgcn_mfma_f32_16x16x32_bf16(qf[qi][1], kf1, z, 0, 0, 0);
#pragma unroll
        for (int j = 0; j < 4; ++j) {
          const int idx = qi * 4 + j;
          const int q = qw + qi * 16 + g4 + j;
          float s = z[j];
          if ((causal && k > q) || !kvalid) s = NEG_INF_F;
          const float mn = fmaxf(m[idx], s);
          l[idx] = l[idx] * __expf(m[idx] - mn) + __expf(s - mn);
          m[idx] = mn;
        }
      }
    }
  }
  // lane butterfly within 16-lane k-groups
#pragma unroll
  for (int off = 1; off < 16; off <<= 1) {
#pragma unroll
    for (int idx = 0; idx < 8; ++idx) {
      const float mo = __shfl_xor(m[idx], off);
      const float lo = __shfl_xor(l[idx], off);
      const float mn = fmaxf(m[idx], mo);
      l[idx] = l[idx] * __expf(m[idx] - mn) + lo * __expf(mo - mn);
      m[idx] = mn;
    }
  }
  // cross-wave merge via LDS
  if (lr == 0) {
#pragma unroll
    for (int qi = 0; qi < 2; ++qi)
#pragma unroll
      for (int j = 0; j < 4; ++j) {
        const int row = qi * 16 + g4 + j;
        ml[wid][row][0] = m[qi * 4 + j];
        ml[wid][row][1] = l[qi * 4 + j];
      }
  }
  __syncthreads();
  float li8[8];
#pragma unroll
  for (int qi = 0; qi < 2; ++qi)
#pragma unroll
    for (int j = 0; j < 4; ++j) {
      const int idx = qi * 4 + j;
      const int row = qi * 16 + g4 + j;
      float mf = ml[0][row][0], lf = ml[0][row][1];
#pragma unroll
      for (int w = 1; w < 4; ++w) {
        const float mo = ml[w][row][0], lo = ml[w][row][1];
        const float mn = fmaxf(mf, mo);
        lf = lf * __expf(mf - mn) + lo * __expf(mo - mn);
        mf = mn;
      }
      m[idx] = mf;
      li8[idx] = 1.0f / lf;
    }

  // ---- pass 2: alpha + partial PV over this wave's k-steps ----
  f32x4 cacc[2][4] = {};

  for (int st = wid; st < nsteps; st += 4) {
    const int kc = st * 32;
#pragma unroll
    for (int h2 = 0; h2 < 2; ++h2) {
      const int kcc = kc + h2 * 16;
      bf16x8 kf0 = *(const bf16x8*)(Kp + (size_t)(kcc + lr) * DK_ + lk8);
      bf16x8 kf1 = *(const bf16x8*)(Kp + (size_t)(kcc + lr) * DK_ + 32 + lk8);
      const int k = kcc + lr;
      const bool kvalid = (pad[b * S_ + k] == 0);
#pragma unroll
      for (int qi = 0; qi < 2; ++qi) {
        f32x4 z = {0.f, 0.f, 0.f, 0.f};
        z = __builtin_amdgcn_mfma_f32_16x16x32_bf16(qf[qi][0], kf0, z, 0, 0, 0);
        z = __builtin_amdgcn_mfma_f32_16x16x32_bf16(qf[qi][1], kf1, z, 0, 0, 0);
#pragma unroll
        for (int j = 0; j < 4; ++j) {
          const int idx = qi * 4 + j;
          const int qrl = qi * 16 + g4 + j;
          const int q = qw + qrl;
          float s = z[j];
          if ((causal && k > q) || !kvalid) s = NEG_INF_F;
          const float a = __expf(s - m[idx]) * li8[idx];
          P[wid][qrl][h2 * 16 + lr] = f2b(a);
          const int v = h2 * 16 + lr;
          const int cp = (v >> 2) ^ (qrl & 7);      // chunk XOR swizzle
          Af[wid][qrl][cp * 4 + (v & 3)] = a;
        }
      }
    }
    asm volatile("s_waitcnt lgkmcnt(0)" ::: "memory");
    __builtin_amdgcn_sched_barrier(0);

    // coalesced alpha write: 32 rows x 128B for this wave's chunk
#pragma unroll
    for (int p = 0; p < 4; ++p) {
      const int row = p * 8 + (lane >> 3);
      const int c = lane & 7;
      float4 w = *(const float4*)&Af[wid][row][((c ^ (row & 7)) << 2)];
      *(float4*)(arow + (size_t)(qw + row) * S_ + kc + c * 4) = w;
    }

    // partial PV
    bf16x8 pa[2];
    pa[0] = *(const bf16x8*)&P[wid][lr][lk8];
    pa[1] = *(const bf16x8*)&P[wid][16 + lr][lk8];
#pragma unroll
    for (int di = 0; di < 4; ++di) {
      bf16x8 vf = *(const bf16x8*)(VTb + (size_t)(di * 16 + lr) * S_ + kc + lk8);
      cacc[0][di] = __builtin_amdgcn_mfma_f32_16x16x32_bf16(pa[0], vf,
                                                            cacc[0][di], 0, 0, 0);
      cacc[1][di] = __builtin_amdgcn_mfma_f32_16x16x32_bf16(pa[1], vf,
                                                            cacc[1][di], 0, 0, 0);
    }
  }

  // zero-fill upper-triangular region (8 rows per wave)
  if (causal) {
    const int kz = qw + 32;
    const int c4 = (S_ - kz) >> 2;
#pragma unroll
    for (int rr = 0; rr < 8; ++rr) {
      const int r = wid * 8 + rr;
      float4* bp = (float4*)(arow + (size_t)(qw + r) * S_ + kz);
      for (int i = lane; i < c4; i += 64) bp[i] = make_float4(0.f, 0.f, 0.f, 0.f);
    }
  }

  // ---- reduce PV partials across waves (red aliases P/Af, now dead) ----
  __syncthreads();
  if (wid > 0) {
#pragma unroll
    for (int qi = 0; qi < 2; ++qi)
#pragma unroll
      for (int di = 0; di < 4; ++di)
#pragma unroll
        for (int j = 0; j < 4; ++j)
          red[wid - 1][lane][qi * 16 + di * 4 + j] = cacc[qi][di][j];
  }
  __syncthreads();
  if (wid == 0) {
#pragma unroll
    for (int w = 0; w < 3; ++w)
#pragma unroll
      for (int qi = 0; qi < 2; ++qi)
#pragma unroll
        for (int di = 0; di < 4; ++di)
#pragma unroll
          for (int j = 0; j < 4; ++j)
            cacc[qi][di][j] += red[w][lane][qi * 16 + di * 4 + j];

#pragma unroll
    for (int qi = 0; qi < 2; ++qi)
#pragma unroll
      for (int di = 0; di < 4; ++di)
#pragma unroll
        for (int j = 0; j < 4; ++j) {
          const int q = qw + qi * 16 + g4 + j;
          const int dk = di * 16 + lr;
          ctxb[((size_t)(b * S_ + q)) * D_ + hh * DK_ + dk] =
              f2b(cacc[qi][di][j]);
        }
  }
}

// ---------------------------------------------------------------------------
// k_oproj: out = ctxb(bf16) @ Wo^T + bo, f32 [M][D].
// ---------------------------------------------------------------------------
__global__ __launch_bounds__(256) void k_oproj(const short* __restrict__ Ab,
                                               const short* __restrict__ Wb,
                                               const float* __restrict__ bias,
                                               float* __restrict__ outf) {
  __shared__ short As[128][40];
  __shared__ short Bs[128][40];
  const int tid = threadIdx.x;
  const int m0 = blockIdx.y * 128, n0 = blockIdx.x * 128;
  const int wid = tid >> 6, lane = tid & 63;
  const int lr = lane & 15, lk8 = (lane >> 4) * 8;
  const int wm = (wid >> 1) * 64, wn = (wid & 1) * 64;

  f32x4 acc[4][4] = {};

  for (int kt = 0; kt < D_; kt += 32) {
#pragma unroll
    for (int i = 0; i < 2; ++i) {
      int li = tid + i * 256;
      int r = li >> 2, g = li & 3;
      int4 a = *(const int4*)(Ab + (size_t)(m0 + r) * D_ + kt + g * 8);
      *(int4*)&As[r][g * 8] = a;
      int4 w = *(const int4*)(Wb + (size_t)(n0 + r) * D_ + kt + g * 8);
      *(int4*)&Bs[r][g * 8] = w;
    }
    __syncthreads();

    bf16x8 af[4], bf[4];
#pragma unroll
    for (int x = 0; x < 4; ++x) {
      af[x] = *(const bf16x8*)&As[wm + x * 16 + lr][lk8];
      bf[x] = *(const bf16x8*)&Bs[wn + x * 16 + lr][lk8];
    }
#pragma unroll
    for (int mi = 0; mi < 4; ++mi)
#pragma unroll
      for (int ni = 0; ni < 4; ++ni)
        acc[mi][ni] = __builtin_amdgcn_mfma_f32_16x16x32_bf16(
            af[mi], bf[ni], acc[mi][ni], 0, 0, 0);
    __syncthreads();
  }

#pragma unroll
  for (int mi = 0; mi < 4; ++mi)
#pragma unroll
    for (int ni = 0; ni < 4; ++ni) {
      int n = n0 + wn + ni * 16 + lr;
      float bv = bias[n];
#pragma unroll
      for (int j = 0; j < 4; ++j) {
        int mm = m0 + wm + mi * 16 + (lane >> 4) * 4 + j;
        outf[(size_t)mm * D_ + n] = acc[mi][ni][j] + bv;
      }
    }
}

// ---------------------------------------------------------------------------
extern "C" void kernel_launch(void* const* d_in, const int* in_sizes, int n_in,
                              void* d_out, int out_size, void* d_ws,
                              size_t ws_size, hipStream_t stream) {
  (void)in_sizes; (void)n_in; (void)out_size; (void)ws_size;
  const float* X  = (const float*)d_in[0];
  const float* Wq = (const float*)d_in[1];
  const float* bq = (const float*)d_in[2];
  const float* Wk = (const float*)d_in[3];
  const float* bk = (const float*)d_in[4];
  const float* Wv = (const float*)d_in[5];
  const float* bv = (const float*)d_in[6];
  const float* Wo = (const float*)d_in[7];
  const float* bo = (const float*)d_in[8];
  const int* pad    = (const int*)d_in[9];
  const int* causal = (const int*)d_in[10];

  float* out   = (float*)d_out;                       // [B,S,D] f32
  float* alpha = out + (size_t)2 * S_ * D_;           // [B,H,S,S] f32

  short* wsb = (short*)d_ws;
  const size_t MM = (size_t)1 << 20;                  // 1M shorts
  short* Xb   = wsb;                                  // 4M
  short* Wqb  = wsb + 4 * MM;                         // 1M
  short* Wkb  = wsb + 5 * MM;
  short* Wvb  = wsb + 6 * MM;
  short* Wob  = wsb + 7 * MM;
  short* Qb   = wsb + 8 * MM;                         // 4M each
  short* Kb   = wsb + 12 * MM;
  short* Vb   = wsb + 16 * MM;
  short* VTb  = wsb + 20 * MM;
  short* ctxb = wsb + 24 * MM;                        // 4M

  dim3 blk(256);

  // X + weights -> bf16
  k_cvt5<<<dim3(4096, 5), blk, 0, stream>>>(X, Wq, Wk, Wv, Wo,
                                            Xb, Wqb, Wkb, Wvb, Wob);

  // fused QKV projection (Q pre-scaled by 1/8)
  k_qkv<<<dim3(D_ / 128, M_ / 128, 3), blk, 0, stream>>>(
      Xb, Wqb, Wkb, Wvb, bq, bk, bv, Qb, Kb, Vb);

  // V -> V^T
  k_vt<<<dim3(S_ / 64, BH_), blk, 0, stream>>>(Vb, VTb);

  // merged stats + alpha + PV (4 waves per 32-row q-tile, k-split)
  k_apv<<<dim3(NT_, BH_), blk, 0, stream>>>(Qb, Kb, VTb, pad, causal,
                                            alpha, ctxb);

  // output projection
  k_oproj<<<dim3(D_ / 128, M_ / 128), blk, 0, stream>>>(ctxb, Wob, bo, out);
}

// Round 7
// 353.372 us; speedup vs baseline: 3.4721x; 1.0170x over previous
//
#include <hip/hip_runtime.h>
#include <cstdint>
#include <cstddef>

#define S_   2048
#define D_   1024
#define H_   16
#define DK_  64
#define BH_  32
#define M_   4096
#define NT_  64                      // 32-row q-tiles
#define NEG_INF_F (-3.4028234663852886e38f)

typedef short bf16x8 __attribute__((ext_vector_type(8)));
typedef float f32x4 __attribute__((ext_vector_type(4)));

__device__ __forceinline__ short f2b(float f) {
  union { float f; uint32_t u; } x; x.f = f;
  uint32_t r = (x.u + 0x7fffu + ((x.u >> 16) & 1u)) >> 16;  // RNE
  return (short)r;
}

// ---------------------------------------------------------------------------
// k_cvt6: f32 -> bf16 for X (job 0), 4 weights (jobs 1..4); job 5 builds the
// f32 padding-bias vector (pad==1 -> NEG_INF else 0).
// ---------------------------------------------------------------------------
__global__ __launch_bounds__(256) void k_cvt6(
    const float* __restrict__ X,  const float* __restrict__ Wq,
    const float* __restrict__ Wk, const float* __restrict__ Wv,
    const float* __restrict__ Wo, const int* __restrict__ pad,
    short* __restrict__ Xb,  short* __restrict__ Wqb,
    short* __restrict__ Wkb, short* __restrict__ Wvb,
    short* __restrict__ Wob, float* __restrict__ padb) {
  const int job = blockIdx.y;
  const int i = blockIdx.x * 256 + threadIdx.x;
  if (job == 5) {
    if (i < (2 * S_) / 4) {
      int4 p = ((const int4*)pad)[i];
      float4 o;
      o.x = p.x ? NEG_INF_F : 0.f;  o.y = p.y ? NEG_INF_F : 0.f;
      o.z = p.z ? NEG_INF_F : 0.f;  o.w = p.w ? NEG_INF_F : 0.f;
      ((float4*)padb)[i] = o;
    }
    return;
  }
  const float* src = job == 0 ? X : job == 1 ? Wq : job == 2 ? Wk
                   : job == 3 ? Wv : Wo;
  short* dst = job == 0 ? Xb : job == 1 ? Wqb : job == 2 ? Wkb
             : job == 3 ? Wvb : Wob;
  const int n4 = (job == 0) ? (M_ * D_ / 4) : (D_ * D_ / 4);
  if (i < n4) {
    float4 v = ((const float4*)src)[i];
    short4 s;
    s.x = f2b(v.x); s.y = f2b(v.y); s.z = f2b(v.z); s.w = f2b(v.w);
    ((short4*)dst)[i] = s;
  }
}

// ---------------------------------------------------------------------------
// k_qkv: fused QKV projection.  A = Xb bf16 [M][K]; z selects W/bias/dst.
// Y = (A @ W^T + bias) * (z==0 ? 1/8 : 1), bf16 head layout [B,H,S,DK].
// ---------------------------------------------------------------------------
__global__ __launch_bounds__(256) void k_qkv(
    const short* __restrict__ Ab,
    const short* __restrict__ W0, const short* __restrict__ W1,
    const short* __restrict__ W2,
    const float* __restrict__ b0, const float* __restrict__ b1,
    const float* __restrict__ b2,
    short* __restrict__ o0, short* __restrict__ o1, short* __restrict__ o2) {
  __shared__ short As[128][40];
  __shared__ short Bs[128][40];
  const int z = blockIdx.z;
  const short* Wb = z == 0 ? W0 : z == 1 ? W1 : W2;
  const float* bias = z == 0 ? b0 : z == 1 ? b1 : b2;
  short* outb = z == 0 ? o0 : z == 1 ? o1 : o2;
  const float oscale = (z == 0) ? 0.125f : 1.0f;

  const int tid = threadIdx.x;
  const int m0 = blockIdx.y * 128, n0 = blockIdx.x * 128;
  const int wid = tid >> 6, lane = tid & 63;
  const int lr = lane & 15, lk8 = (lane >> 4) * 8;
  const int wm = (wid >> 1) * 64, wn = (wid & 1) * 64;

  f32x4 acc[4][4] = {};

  for (int kt = 0; kt < D_; kt += 32) {
#pragma unroll
    for (int i = 0; i < 2; ++i) {
      int li = tid + i * 256;
      int r = li >> 2, g = li & 3;
      int4 a = *(const int4*)(Ab + (size_t)(m0 + r) * D_ + kt + g * 8);
      *(int4*)&As[r][g * 8] = a;
      int4 w = *(const int4*)(Wb + (size_t)(n0 + r) * D_ + kt + g * 8);
      *(int4*)&Bs[r][g * 8] = w;
    }
    __syncthreads();

    bf16x8 af[4], bf[4];
#pragma unroll
    for (int x = 0; x < 4; ++x) {
      af[x] = *(const bf16x8*)&As[wm + x * 16 + lr][lk8];
      bf[x] = *(const bf16x8*)&Bs[wn + x * 16 + lr][lk8];
    }
#pragma unroll
    for (int mi = 0; mi < 4; ++mi)
#pragma unroll
      for (int ni = 0; ni < 4; ++ni)
        acc[mi][ni] = __builtin_amdgcn_mfma_f32_16x16x32_bf16(
            af[mi], bf[ni], acc[mi][ni], 0, 0, 0);
    __syncthreads();
  }

#pragma unroll
  for (int mi = 0; mi < 4; ++mi)
#pragma unroll
    for (int ni = 0; ni < 4; ++ni) {
      int n = n0 + wn + ni * 16 + lr;
      float bv = bias[n];
#pragma unroll
      for (int j = 0; j < 4; ++j) {
        int m = m0 + wm + mi * 16 + (lane >> 4) * 4 + j;
        float v = (acc[mi][ni][j] + bv) * oscale;
        int b = m >> 11, s = m & (S_ - 1);
        int h = n >> 6, dk = n & (DK_ - 1);
        outb[(((size_t)(b * H_ + h)) * S_ + s) * DK_ + dk] = f2b(v);
      }
    }
}

// ---------------------------------------------------------------------------
// k_vt: V [BH][S][DK] bf16 -> VT [BH][DK][S] bf16 (64x64 LDS tiles)
// ---------------------------------------------------------------------------
__global__ __launch_bounds__(256) void k_vt(const short* __restrict__ V,
                                            short* __restrict__ VT) {
  __shared__ short t[64][72];
  const int tid = threadIdx.x;
  const int bh = blockIdx.y, s0 = blockIdx.x * 64;
  const short* src = V + ((size_t)bh * S_ + s0) * DK_;
#pragma unroll
  for (int i = 0; i < 2; ++i) {
    int li = tid + i * 256;
    int r = li >> 3, g = li & 7;
    int4 v = *(const int4*)(src + r * DK_ + g * 8);
    *(int4*)&t[r][g * 8] = v;
  }
  __syncthreads();
  short* dst = VT + (size_t)bh * DK_ * S_ + s0;
#pragma unroll
  for (int i = 0; i < 2; ++i) {
    int li = tid + i * 256;
    int dkr = li >> 3, g = li & 7;
    short o[8];
#pragma unroll
    for (int j = 0; j < 8; ++j) o[j] = t[g * 8 + j][dkr];
    *(int4*)(dst + (size_t)dkr * S_ + g * 8) = *(int4*)o;
  }
}

// ---------------------------------------------------------------------------
// k_apv: swapped-QK^T (mfma(K,Q)) flash attention, 4 waves k-split per
// 32-row q-tile.  Lane holds one q-row's k-slice: softmax reduction is
// lane-local (tree + xor16/32 merge); alpha written float4 from registers;
// P packed v_cvt_pk_bf16_f32 + shfl_xor redistribution -> PV MFMA A-frags.
// No per-step LDS.  ctx bf16 [B][S][D].
// ---------------------------------------------------------------------------
__global__ __launch_bounds__(256) void k_apv(const short* __restrict__ Q,
                                             const short* __restrict__ Kb,
                                             const short* __restrict__ VT,
                                             const float* __restrict__ padb,
                                             const int* __restrict__ causalp,
                                             float* __restrict__ alpha,
                                             short* __restrict__ ctxb) {
  __shared__ float red[3][64][32];   // PV partials (waves 1..3)
  __shared__ float ml[4][32][2];     // cross-wave (m,l)

  const int tid = threadIdx.x, wid = tid >> 6, lane = tid & 63;
  const int bh = blockIdx.y;
  const int tile = (NT_ - 1) - blockIdx.x;   // big tiles dispatch first
  const int qw = tile * 32;
  const int lr = lane & 15, lk8 = (lane >> 4) * 8;
  const int g = lane >> 4, g4 = g * 4;
  const int b = bh >> 4, hh = bh & (H_ - 1);
  const short* Qb = Q + (size_t)bh * S_ * DK_;
  const short* Kp = Kb + (size_t)bh * S_ * DK_;
  const short* VTb = VT + (size_t)bh * DK_ * S_;
  const float* pbias = padb + b * S_;
  float* arow = alpha + (size_t)bh * S_ * S_;

  bf16x8 qf[2][2];
#pragma unroll
  for (int qi = 0; qi < 2; ++qi)
#pragma unroll
    for (int h = 0; h < 2; ++h)
      qf[qi][h] = *(const bf16x8*)(Qb + (size_t)(qw + qi * 16 + lr) * DK_ +
                                   h * 32 + lk8);

  const int causal = *causalp;
  const int nsteps = causal ? (tile + 1) : (S_ / 32);

  // ---- pass 1: per-lane (m,l) over this wave's strided k-steps ----
  float m[2] = {-1e30f, -1e30f}, l[2] = {0.f, 0.f};

  for (int st = wid; st < nsteps; st += 4) {
    const int kc = st * 32;
    const bool diag = causal && (st == tile);
    float s[2][8];
#pragma unroll
    for (int h2 = 0; h2 < 2; ++h2) {
      const int kcc = kc + h2 * 16;
      bf16x8 kf0 = *(const bf16x8*)(Kp + (size_t)(kcc + lr) * DK_ + lk8);
      bf16x8 kf1 = *(const bf16x8*)(Kp + (size_t)(kcc + lr) * DK_ + 32 + lk8);
      float4 pb = *(const float4*)(pbias + kcc + g4);
#pragma unroll
      for (int qi = 0; qi < 2; ++qi) {
        f32x4 z = {0.f, 0.f, 0.f, 0.f};
        z = __builtin_amdgcn_mfma_f32_16x16x32_bf16(kf0, qf[qi][0], z, 0, 0, 0);
        z = __builtin_amdgcn_mfma_f32_16x16x32_bf16(kf1, qf[qi][1], z, 0, 0, 0);
        const int q = qw + qi * 16 + lr;
#pragma unroll
        for (int j = 0; j < 4; ++j) {
          float sv = z[j] + ((const float*)&pb)[j];
          if (diag && (kcc + g4 + j > q)) sv = NEG_INF_F;
          s[qi][h2 * 4 + j] = sv;
        }
      }
    }
#pragma unroll
    for (int qi = 0; qi < 2; ++qi) {
      float pm = fmaxf(fmaxf(fmaxf(s[qi][0], s[qi][1]), fmaxf(s[qi][2], s[qi][3])),
                       fmaxf(fmaxf(s[qi][4], s[qi][5]), fmaxf(s[qi][6], s[qi][7])));
      const float mn = fmaxf(m[qi], pm);
      float sum = 0.f;
#pragma unroll
      for (int jj = 0; jj < 8; ++jj) sum += __expf(s[qi][jj] - mn);
      l[qi] = l[qi] * __expf(m[qi] - mn) + sum;
      m[qi] = mn;
    }
  }

  // merge across the 4 k-groups (lanes lr, 16+lr, 32+lr, 48+lr)
#pragma unroll
  for (int off = 16; off <= 32; off <<= 1) {
#pragma unroll
    for (int qi = 0; qi < 2; ++qi) {
      const float mo = __shfl_xor(m[qi], off);
      const float lo = __shfl_xor(l[qi], off);
      const float mn = fmaxf(m[qi], mo);
      l[qi] = l[qi] * __expf(m[qi] - mn) + lo * __expf(mo - mn);
      m[qi] = mn;
    }
  }
  if (g == 0) {
    ml[wid][lr][0] = m[0];      ml[wid][lr][1] = l[0];
    ml[wid][16 + lr][0] = m[1]; ml[wid][16 + lr][1] = l[1];
  }
  __syncthreads();
  float li[2];
#pragma unroll
  for (int qi = 0; qi < 2; ++qi) {
    const int row = qi * 16 + lr;
    float mf = ml[0][row][0], lf = ml[0][row][1];
#pragma unroll
    for (int w = 1; w < 4; ++w) {
      const float mo = ml[w][row][0], lo = ml[w][row][1];
      const float mn = fmaxf(mf, mo);
      lf = lf * __expf(mf - mn) + lo * __expf(mo - mn);
      mf = mn;
    }
    m[qi] = mf;
    li[qi] = 1.0f / lf;
  }

  // ---- pass 2: alpha + partial PV over this wave's k-steps ----
  f32x4 cacc[2][4] = {};

  for (int st = wid; st < nsteps; st += 4) {
    const int kc = st * 32;
    const bool diag = causal && (st == tile);
    uint32_t pk[2][2][2];
#pragma unroll
    for (int h2 = 0; h2 < 2; ++h2) {
      const int kcc = kc + h2 * 16;
      bf16x8 kf0 = *(const bf16x8*)(Kp + (size_t)(kcc + lr) * DK_ + lk8);
      bf16x8 kf1 = *(const bf16x8*)(Kp + (size_t)(kcc + lr) * DK_ + 32 + lk8);
      float4 pb = *(const float4*)(pbias + kcc + g4);
#pragma unroll
      for (int qi = 0; qi < 2; ++qi) {
        f32x4 z = {0.f, 0.f, 0.f, 0.f};
        z = __builtin_amdgcn_mfma_f32_16x16x32_bf16(kf0, qf[qi][0], z, 0, 0, 0);
        z = __builtin_amdgcn_mfma_f32_16x16x32_bf16(kf1, qf[qi][1], z, 0, 0, 0);
        const int q = qw + qi * 16 + lr;
        float a[4];
#pragma unroll
        for (int j = 0; j < 4; ++j) {
          float sv = z[j] + ((const float*)&pb)[j];
          if (diag && (kcc + g4 + j > q)) sv = NEG_INF_F;
          a[j] = __expf(sv - m[qi]) * li[qi];
        }
        *(float4*)(arow + (size_t)q * S_ + kcc + g4) =
            make_float4(a[0], a[1], a[2], a[3]);
        asm volatile("v_cvt_pk_bf16_f32 %0, %1, %2"
                     : "=v"(pk[qi][h2][0]) : "v"(a[0]), "v"(a[1]));
        asm volatile("v_cvt_pk_bf16_f32 %0, %1, %2"
                     : "=v"(pk[qi][h2][1]) : "v"(a[2]), "v"(a[3]));
      }
    }

    // redistribute P to MFMA A-frags: lane g needs X(h=g>>1, 2(g&1)..+1)
    bf16x8 paf[2];
#pragma unroll
    for (int qi = 0; qi < 2; ++qi) {
      const uint32_t x00 = pk[qi][0][0], x01 = pk[qi][0][1];
      const uint32_t x10 = pk[qi][1][0], x11 = pk[qi][1][1];
      const uint32_t y00 = __shfl_xor((int)x00, 32);
      const uint32_t y01 = __shfl_xor((int)x01, 32);
      const uint32_t y10 = __shfl_xor((int)x10, 32);
      const uint32_t y11 = __shfl_xor((int)x11, 32);
      const bool hi2 = (g >= 2);
      const uint32_t a0 = hi2 ? x10 : x00, a1 = hi2 ? x11 : x01;
      const uint32_t b0 = hi2 ? y10 : y00, b1 = hi2 ? y11 : y01;
      const uint32_t cA0 = __shfl_xor((int)a0, 16);
      const uint32_t cA1 = __shfl_xor((int)a1, 16);
      const uint32_t cB0 = __shfl_xor((int)b0, 16);
      const uint32_t cB1 = __shfl_xor((int)b1, 16);
      const bool sel_a = (g == 0) || (g == 3);
      const uint32_t u0 = sel_a ? a0 : b0, u1 = sel_a ? a1 : b1;
      const uint32_t v0 = sel_a ? cA0 : cB0, v1 = sel_a ? cA1 : cB1;
      const bool odd = g & 1;
      union { uint32_t u[4]; bf16x8 v; } uu;
      uu.u[0] = odd ? v0 : u0;  uu.u[1] = odd ? v1 : u1;
      uu.u[2] = odd ? u0 : v0;  uu.u[3] = odd ? u1 : v1;
      paf[qi] = uu.v;
    }

#pragma unroll
    for (int di = 0; di < 4; ++di) {
      bf16x8 vf = *(const bf16x8*)(VTb + (size_t)(di * 16 + lr) * S_ + kc + lk8);
      cacc[0][di] = __builtin_amdgcn_mfma_f32_16x16x32_bf16(paf[0], vf,
                                                            cacc[0][di], 0, 0, 0);
      cacc[1][di] = __builtin_amdgcn_mfma_f32_16x16x32_bf16(paf[1], vf,
                                                            cacc[1][di], 0, 0, 0);
    }
  }

  // zero-fill upper-triangular region (8 rows per wave)
  if (causal) {
    const int kz = qw + 32;
    const int c4 = (S_ - kz) >> 2;
#pragma unroll
    for (int rr = 0; rr < 8; ++rr) {
      const int r = wid * 8 + rr;
      float4* bp = (float4*)(arow + (size_t)(qw + r) * S_ + kz);
      for (int i = lane; i < c4; i += 64) bp[i] = make_float4(0.f, 0.f, 0.f, 0.f);
    }
  }

  // ---- reduce PV partials across waves ----
  __syncthreads();
  if (wid > 0) {
#pragma unroll
    for (int qi = 0; qi < 2; ++qi)
#pragma unroll
      for (int di = 0; di < 4; ++di)
#pragma unroll
        for (int j = 0; j < 4; ++j)
          red[wid - 1][lane][qi * 16 + di * 4 + j] = cacc[qi][di][j];
  }
  __syncthreads();
  if (wid == 0) {
#pragma unroll
    for (int w = 0; w < 3; ++w)
#pragma unroll
      for (int qi = 0; qi < 2; ++qi)
#pragma unroll
        for (int di = 0; di < 4; ++di)
#pragma unroll
          for (int j = 0; j < 4; ++j)
            cacc[qi][di][j] += red[w][lane][qi * 16 + di * 4 + j];

#pragma unroll
    for (int qi = 0; qi < 2; ++qi)
#pragma unroll
      for (int di = 0; di < 4; ++di)
#pragma unroll
        for (int j = 0; j < 4; ++j) {
          const int q = qw + qi * 16 + g4 + j;
          const int dk = di * 16 + lr;
          ctxb[((size_t)(b * S_ + q)) * D_ + hh * DK_ + dk] =
              f2b(cacc[qi][di][j]);
        }
  }
}

// ---------------------------------------------------------------------------
// k_oproj: out = ctxb(bf16) @ Wo^T + bo, f32 [M][D].
// ---------------------------------------------------------------------------
__global__ __launch_bounds__(256) void k_oproj(const short* __restrict__ Ab,
                                               const short* __restrict__ Wb,
                                               const float* __restrict__ bias,
                                               float* __restrict__ outf) {
  __shared__ short As[128][40];
  __shared__ short Bs[128][40];
  const int tid = threadIdx.x;
  const int m0 = blockIdx.y * 128, n0 = blockIdx.x * 128;
  const int wid = tid >> 6, lane = tid & 63;
  const int lr = lane & 15, lk8 = (lane >> 4) * 8;
  const int wm = (wid >> 1) * 64, wn = (wid & 1) * 64;

  f32x4 acc[4][4] = {};

  for (int kt = 0; kt < D_; kt += 32) {
#pragma unroll
    for (int i = 0; i < 2; ++i) {
      int li = tid + i * 256;
      int r = li >> 2, g = li & 3;
      int4 a = *(const int4*)(Ab + (size_t)(m0 + r) * D_ + kt + g * 8);
      *(int4*)&As[r][g * 8] = a;
      int4 w = *(const int4*)(Wb + (size_t)(n0 + r) * D_ + kt + g * 8);
      *(int4*)&Bs[r][g * 8] = w;
    }
    __syncthreads();

    bf16x8 af[4], bf[4];
#pragma unroll
    for (int x = 0; x < 4; ++x) {
      af[x] = *(const bf16x8*)&As[wm + x * 16 + lr][lk8];
      bf[x] = *(const bf16x8*)&Bs[wn + x * 16 + lr][lk8];
    }
#pragma unroll
    for (int mi = 0; mi < 4; ++mi)
#pragma unroll
      for (int ni = 0; ni < 4; ++ni)
        acc[mi][ni] = __builtin_amdgcn_mfma_f32_16x16x32_bf16(
            af[mi], bf[ni], acc[mi][ni], 0, 0, 0);
    __syncthreads();
  }

#pragma unroll
  for (int mi = 0; mi < 4; ++mi)
#pragma unroll
    for (int ni = 0; ni < 4; ++ni) {
      int n = n0 + wn + ni * 16 + lr;
      float bv = bias[n];
#pragma unroll
      for (int j = 0; j < 4; ++j) {
        int mm = m0 + wm + mi * 16 + (lane >> 4) * 4 + j;
        outf[(size_t)mm * D_ + n] = acc[mi][ni][j] + bv;
      }
    }
}

// ---------------------------------------------------------------------------
extern "C" void kernel_launch(void* const* d_in, const int* in_sizes, int n_in,
                              void* d_out, int out_size, void* d_ws,
                              size_t ws_size, hipStream_t stream) {
  (void)in_sizes; (void)n_in; (void)out_size; (void)ws_size;
  const float* X  = (const float*)d_in[0];
  const float* Wq = (const float*)d_in[1];
  const float* bq = (const float*)d_in[2];
  const float* Wk = (const float*)d_in[3];
  const float* bk = (const float*)d_in[4];
  const float* Wv = (const float*)d_in[5];
  const float* bv = (const float*)d_in[6];
  const float* Wo = (const float*)d_in[7];
  const float* bo = (const float*)d_in[8];
  const int* pad    = (const int*)d_in[9];
  const int* causal = (const int*)d_in[10];

  float* out   = (float*)d_out;                       // [B,S,D] f32
  float* alpha = out + (size_t)2 * S_ * D_;           // [B,H,S,S] f32

  short* wsb = (short*)d_ws;
  const size_t MM = (size_t)1 << 20;                  // 1M shorts
  short* Xb   = wsb;                                  // 4M
  short* Wqb  = wsb + 4 * MM;                         // 1M
  short* Wkb  = wsb + 5 * MM;
  short* Wvb  = wsb + 6 * MM;
  short* Wob  = wsb + 7 * MM;
  short* Qb   = wsb + 8 * MM;                         // 4M each
  short* Kb   = wsb + 12 * MM;
  short* Vb   = wsb + 16 * MM;
  short* VTb  = wsb + 20 * MM;
  short* ctxb = wsb + 24 * MM;                        // 4M
  float* padb = (float*)(wsb + 28 * MM);              // 4K f32

  dim3 blk(256);

  // X + weights -> bf16; padding bias
  k_cvt6<<<dim3(4096, 6), blk, 0, stream>>>(X, Wq, Wk, Wv, Wo, pad,
                                            Xb, Wqb, Wkb, Wvb, Wob, padb);

  // fused QKV projection (Q pre-scaled by 1/8)
  k_qkv<<<dim3(D_ / 128, M_ / 128, 3), blk, 0, stream>>>(
      Xb, Wqb, Wkb, Wvb, bq, bk, bv, Qb, Kb, Vb);

  // V -> V^T
  k_vt<<<dim3(S_ / 64, BH_), blk, 0, stream>>>(Vb, VTb);

  // swapped-operand flash attention + alpha write (4 waves, k-split)
  k_apv<<<dim3(NT_, BH_), blk, 0, stream>>>(Qb, Kb, VTb, padb, causal,
                                            alpha, ctxb);

  // output projection
  k_oproj<<<dim3(D_ / 128, M_ / 128), blk, 0, stream>>>(ctxb, Wob, bo, out);
}

// Round 8
// 339.351 us; speedup vs baseline: 3.6156x; 1.0413x over previous
//
#include <hip/hip_runtime.h>
#include <cstdint>
#include <cstddef>

#define S_   2048
#define D_   1024
#define H_   16
#define DK_  64
#define BH_  32
#define M_   4096
#define NT_  64                      // 32-row q-tiles
#define NEG_INF_F (-3.4028234663852886e38f)

typedef short bf16x8 __attribute__((ext_vector_type(8)));
typedef float f32x4 __attribute__((ext_vector_type(4)));

__device__ __forceinline__ short f2b(float f) {
  union { float f; uint32_t u; } x; x.f = f;
  uint32_t r = (x.u + 0x7fffu + ((x.u >> 16) & 1u)) >> 16;  // RNE
  return (short)r;
}

// ---------------------------------------------------------------------------
// k_cvt6: f32 -> bf16 for X (job 0), 4 weights (jobs 1..4); job 5 builds the
// f32 padding-bias vector (pad==1 -> NEG_INF else 0).
// ---------------------------------------------------------------------------
__global__ __launch_bounds__(256) void k_cvt6(
    const float* __restrict__ X,  const float* __restrict__ Wq,
    const float* __restrict__ Wk, const float* __restrict__ Wv,
    const float* __restrict__ Wo, const int* __restrict__ pad,
    short* __restrict__ Xb,  short* __restrict__ Wqb,
    short* __restrict__ Wkb, short* __restrict__ Wvb,
    short* __restrict__ Wob, float* __restrict__ padb) {
  const int job = blockIdx.y;
  const int i = blockIdx.x * 256 + threadIdx.x;
  if (job == 5) {
    if (i < (2 * S_) / 4) {
      int4 p = ((const int4*)pad)[i];
      float4 o;
      o.x = p.x ? NEG_INF_F : 0.f;  o.y = p.y ? NEG_INF_F : 0.f;
      o.z = p.z ? NEG_INF_F : 0.f;  o.w = p.w ? NEG_INF_F : 0.f;
      ((float4*)padb)[i] = o;
    }
    return;
  }
  const float* src = job == 0 ? X : job == 1 ? Wq : job == 2 ? Wk
                   : job == 3 ? Wv : Wo;
  short* dst = job == 0 ? Xb : job == 1 ? Wqb : job == 2 ? Wkb
             : job == 3 ? Wvb : Wob;
  const int n4 = (job == 0) ? (M_ * D_ / 4) : (D_ * D_ / 4);
  if (i < n4) {
    float4 v = ((const float4*)src)[i];
    short4 s;
    s.x = f2b(v.x); s.y = f2b(v.y); s.z = f2b(v.z); s.w = f2b(v.w);
    ((short4*)dst)[i] = s;
  }
}

// ---------------------------------------------------------------------------
// k_qkv: fused QKV projection.  A = Xb bf16 [M][K]; z selects W/bias/dst.
// XCD-aware decode: xcd = flat%8 == m-panel%8 so each XCD reuses 4 X-panels.
// ---------------------------------------------------------------------------
__global__ __launch_bounds__(256) void k_qkv(
    const short* __restrict__ Ab,
    const short* __restrict__ W0, const short* __restrict__ W1,
    const short* __restrict__ W2,
    const float* __restrict__ b0, const float* __restrict__ b1,
    const float* __restrict__ b2,
    short* __restrict__ o0, short* __restrict__ o1, short* __restrict__ o2) {
  __shared__ short As[128][40];
  __shared__ short Bs[128][40];
  const int z = blockIdx.z;
  const short* Wb = z == 0 ? W0 : z == 1 ? W1 : W2;
  const float* bias = z == 0 ? b0 : z == 1 ? b1 : b2;
  short* outb = z == 0 ? o0 : z == 1 ? o1 : o2;
  const float oscale = (z == 0) ? 0.125f : 1.0f;

  // XCD swizzle: flat%8 = hw XCD; put m-panel on xcd, n-panel varies within
  const int flat = blockIdx.x + 8 * blockIdx.y;     // 0..255
  const int xcd = flat & 7, slot = flat >> 3;       // slot 0..31
  const int m0 = (xcd + 8 * (slot & 3)) * 128;      // 32 m-panels
  const int n0 = (slot >> 2) * 128;                 // 8 n-panels

  const int tid = threadIdx.x;
  const int wid = tid >> 6, lane = tid & 63;
  const int lr = lane & 15, lk8 = (lane >> 4) * 8;
  const int wm = (wid >> 1) * 64, wn = (wid & 1) * 64;

  f32x4 acc[4][4] = {};

  for (int kt = 0; kt < D_; kt += 32) {
#pragma unroll
    for (int i = 0; i < 2; ++i) {
      int li = tid + i * 256;
      int r = li >> 2, g = li & 3;
      int4 a = *(const int4*)(Ab + (size_t)(m0 + r) * D_ + kt + g * 8);
      *(int4*)&As[r][g * 8] = a;
      int4 w = *(const int4*)(Wb + (size_t)(n0 + r) * D_ + kt + g * 8);
      *(int4*)&Bs[r][g * 8] = w;
    }
    __syncthreads();

    bf16x8 af[4], bf[4];
#pragma unroll
    for (int x = 0; x < 4; ++x) {
      af[x] = *(const bf16x8*)&As[wm + x * 16 + lr][lk8];
      bf[x] = *(const bf16x8*)&Bs[wn + x * 16 + lr][lk8];
    }
#pragma unroll
    for (int mi = 0; mi < 4; ++mi)
#pragma unroll
      for (int ni = 0; ni < 4; ++ni)
        acc[mi][ni] = __builtin_amdgcn_mfma_f32_16x16x32_bf16(
            af[mi], bf[ni], acc[mi][ni], 0, 0, 0);
    __syncthreads();
  }

#pragma unroll
  for (int mi = 0; mi < 4; ++mi)
#pragma unroll
    for (int ni = 0; ni < 4; ++ni) {
      int n = n0 + wn + ni * 16 + lr;
      float bv = bias[n];
#pragma unroll
      for (int j = 0; j < 4; ++j) {
        int m = m0 + wm + mi * 16 + (lane >> 4) * 4 + j;
        float v = (acc[mi][ni][j] + bv) * oscale;
        int b = m >> 11, s = m & (S_ - 1);
        int h = n >> 6, dk = n & (DK_ - 1);
        outb[(((size_t)(b * H_ + h)) * S_ + s) * DK_ + dk] = f2b(v);
      }
    }
}

// ---------------------------------------------------------------------------
// k_vt: V [BH][S][DK] bf16 -> VT [BH][DK][S] bf16 (64x64 LDS tiles)
// ---------------------------------------------------------------------------
__global__ __launch_bounds__(256) void k_vt(const short* __restrict__ V,
                                            short* __restrict__ VT) {
  __shared__ short t[64][72];
  const int tid = threadIdx.x;
  const int bh = blockIdx.y, s0 = blockIdx.x * 64;
  const short* src = V + ((size_t)bh * S_ + s0) * DK_;
#pragma unroll
  for (int i = 0; i < 2; ++i) {
    int li = tid + i * 256;
    int r = li >> 3, g = li & 7;
    int4 v = *(const int4*)(src + r * DK_ + g * 8);
    *(int4*)&t[r][g * 8] = v;
  }
  __syncthreads();
  short* dst = VT + (size_t)bh * DK_ * S_ + s0;
#pragma unroll
  for (int i = 0; i < 2; ++i) {
    int li = tid + i * 256;
    int dkr = li >> 3, g = li & 7;
    short o[8];
#pragma unroll
    for (int j = 0; j < 8; ++j) o[j] = t[g * 8 + j][dkr];
    *(int4*)(dst + (size_t)dkr * S_ + g * 8) = *(int4*)o;
  }
}

// ---------------------------------------------------------------------------
// k_apv: swapped-QK^T flash attention + alpha write, 4 waves k-split per
// 32-row q-tile.  XCD-aware 1D grid: xcd = id%8, bh = 8*(slot%4)+xcd so each
// XCD serves only 4 (b,h) pairs -> K/VT panels stay L2-resident (2MB/XCD).
// ---------------------------------------------------------------------------
__global__ __launch_bounds__(256) void k_apv(const short* __restrict__ Q,
                                             const short* __restrict__ Kb,
                                             const short* __restrict__ VT,
                                             const float* __restrict__ padb,
                                             const int* __restrict__ causalp,
                                             float* __restrict__ alpha,
                                             short* __restrict__ ctxb) {
  __shared__ float red[3][64][32];   // PV partials (waves 1..3)
  __shared__ float ml[4][32][2];     // cross-wave (m,l)

  const int tid = threadIdx.x, wid = tid >> 6, lane = tid & 63;
  // XCD decode: 2048 blocks; big tiles first within each XCD
  const int id = blockIdx.x;
  const int xcd = id & 7, slot = id >> 3;           // slot 0..255
  const int bh = 8 * (slot & 3) + xcd;              // 4 bh per XCD
  const int tile = (NT_ - 1) - (slot >> 2);         // 63..0
  const int qw = tile * 32;
  const int lr = lane & 15, lk8 = (lane >> 4) * 8;
  const int g = lane >> 4, g4 = g * 4;
  const int b = bh >> 4, hh = bh & (H_ - 1);
  const short* Qb = Q + (size_t)bh * S_ * DK_;
  const short* Kp = Kb + (size_t)bh * S_ * DK_;
  const short* VTb = VT + (size_t)bh * DK_ * S_;
  const float* pbias = padb + b * S_;
  float* arow = alpha + (size_t)bh * S_ * S_;

  bf16x8 qf[2][2];
#pragma unroll
  for (int qi = 0; qi < 2; ++qi)
#pragma unroll
    for (int h = 0; h < 2; ++h)
      qf[qi][h] = *(const bf16x8*)(Qb + (size_t)(qw + qi * 16 + lr) * DK_ +
                                   h * 32 + lk8);

  const int causal = *causalp;
  const int nsteps = causal ? (tile + 1) : (S_ / 32);

  // ---- pass 1: per-lane (m,l) over this wave's strided k-steps ----
  float m[2] = {-1e30f, -1e30f}, l[2] = {0.f, 0.f};

  for (int st = wid; st < nsteps; st += 4) {
    const int kc = st * 32;
    const bool diag = causal && (st == tile);
    float s[2][8];
#pragma unroll
    for (int h2 = 0; h2 < 2; ++h2) {
      const int kcc = kc + h2 * 16;
      bf16x8 kf0 = *(const bf16x8*)(Kp + (size_t)(kcc + lr) * DK_ + lk8);
      bf16x8 kf1 = *(const bf16x8*)(Kp + (size_t)(kcc + lr) * DK_ + 32 + lk8);
      float4 pb = *(const float4*)(pbias + kcc + g4);
#pragma unroll
      for (int qi = 0; qi < 2; ++qi) {
        f32x4 z = {0.f, 0.f, 0.f, 0.f};
        z = __builtin_amdgcn_mfma_f32_16x16x32_bf16(kf0, qf[qi][0], z, 0, 0, 0);
        z = __builtin_amdgcn_mfma_f32_16x16x32_bf16(kf1, qf[qi][1], z, 0, 0, 0);
        const int q = qw + qi * 16 + lr;
#pragma unroll
        for (int j = 0; j < 4; ++j) {
          float sv = z[j] + ((const float*)&pb)[j];
          if (diag && (kcc + g4 + j > q)) sv = NEG_INF_F;
          s[qi][h2 * 4 + j] = sv;
        }
      }
    }
#pragma unroll
    for (int qi = 0; qi < 2; ++qi) {
      float pm = fmaxf(fmaxf(fmaxf(s[qi][0], s[qi][1]), fmaxf(s[qi][2], s[qi][3])),
                       fmaxf(fmaxf(s[qi][4], s[qi][5]), fmaxf(s[qi][6], s[qi][7])));
      const float mn = fmaxf(m[qi], pm);
      float sum = 0.f;
#pragma unroll
      for (int jj = 0; jj < 8; ++jj) sum += __expf(s[qi][jj] - mn);
      l[qi] = l[qi] * __expf(m[qi] - mn) + sum;
      m[qi] = mn;
    }
  }

  // merge across the 4 k-groups (lanes lr, 16+lr, 32+lr, 48+lr)
#pragma unroll
  for (int off = 16; off <= 32; off <<= 1) {
#pragma unroll
    for (int qi = 0; qi < 2; ++qi) {
      const float mo = __shfl_xor(m[qi], off);
      const float lo = __shfl_xor(l[qi], off);
      const float mn = fmaxf(m[qi], mo);
      l[qi] = l[qi] * __expf(m[qi] - mn) + lo * __expf(mo - mn);
      m[qi] = mn;
    }
  }
  if (g == 0) {
    ml[wid][lr][0] = m[0];      ml[wid][lr][1] = l[0];
    ml[wid][16 + lr][0] = m[1]; ml[wid][16 + lr][1] = l[1];
  }
  __syncthreads();
  float li[2];
#pragma unroll
  for (int qi = 0; qi < 2; ++qi) {
    const int row = qi * 16 + lr;
    float mf = ml[0][row][0], lf = ml[0][row][1];
#pragma unroll
    for (int w = 1; w < 4; ++w) {
      const float mo = ml[w][row][0], lo = ml[w][row][1];
      const float mn = fmaxf(mf, mo);
      lf = lf * __expf(mf - mn) + lo * __expf(mo - mn);
      mf = mn;
    }
    m[qi] = mf;
    li[qi] = 1.0f / lf;
  }

  // ---- pass 2: alpha + partial PV over this wave's k-steps ----
  f32x4 cacc[2][4] = {};

  for (int st = wid; st < nsteps; st += 4) {
    const int kc = st * 32;
    const bool diag = causal && (st == tile);
    uint32_t pk[2][2][2];
#pragma unroll
    for (int h2 = 0; h2 < 2; ++h2) {
      const int kcc = kc + h2 * 16;
      bf16x8 kf0 = *(const bf16x8*)(Kp + (size_t)(kcc + lr) * DK_ + lk8);
      bf16x8 kf1 = *(const bf16x8*)(Kp + (size_t)(kcc + lr) * DK_ + 32 + lk8);
      float4 pb = *(const float4*)(pbias + kcc + g4);
#pragma unroll
      for (int qi = 0; qi < 2; ++qi) {
        f32x4 z = {0.f, 0.f, 0.f, 0.f};
        z = __builtin_amdgcn_mfma_f32_16x16x32_bf16(kf0, qf[qi][0], z, 0, 0, 0);
        z = __builtin_amdgcn_mfma_f32_16x16x32_bf16(kf1, qf[qi][1], z, 0, 0, 0);
        const int q = qw + qi * 16 + lr;
        float a[4];
#pragma unroll
        for (int j = 0; j < 4; ++j) {
          float sv = z[j] + ((const float*)&pb)[j];
          if (diag && (kcc + g4 + j > q)) sv = NEG_INF_F;
          a[j] = __expf(sv - m[qi]) * li[qi];
        }
        *(float4*)(arow + (size_t)q * S_ + kcc + g4) =
            make_float4(a[0], a[1], a[2], a[3]);
        asm volatile("v_cvt_pk_bf16_f32 %0, %1, %2"
                     : "=v"(pk[qi][h2][0]) : "v"(a[0]), "v"(a[1]));
        asm volatile("v_cvt_pk_bf16_f32 %0, %1, %2"
                     : "=v"(pk[qi][h2][1]) : "v"(a[2]), "v"(a[3]));
      }
    }

    // redistribute P to MFMA A-frags: lane g needs X(h=g>>1, 2(g&1)..+1)
    bf16x8 paf[2];
#pragma unroll
    for (int qi = 0; qi < 2; ++qi) {
      const uint32_t x00 = pk[qi][0][0], x01 = pk[qi][0][1];
      const uint32_t x10 = pk[qi][1][0], x11 = pk[qi][1][1];
      const uint32_t y00 = __shfl_xor((int)x00, 32);
      const uint32_t y01 = __shfl_xor((int)x01, 32);
      const uint32_t y10 = __shfl_xor((int)x10, 32);
      const uint32_t y11 = __shfl_xor((int)x11, 32);
      const bool hi2 = (g >= 2);
      const uint32_t a0 = hi2 ? x10 : x00, a1 = hi2 ? x11 : x01;
      const uint32_t b0 = hi2 ? y10 : y00, b1 = hi2 ? y11 : y01;
      const uint32_t cA0 = __shfl_xor((int)a0, 16);
      const uint32_t cA1 = __shfl_xor((int)a1, 16);
      const uint32_t cB0 = __shfl_xor((int)b0, 16);
      const uint32_t cB1 = __shfl_xor((int)b1, 16);
      const bool sel_a = (g == 0) || (g == 3);
      const uint32_t u0 = sel_a ? a0 : b0, u1 = sel_a ? a1 : b1;
      const uint32_t v0 = sel_a ? cA0 : cB0, v1 = sel_a ? cA1 : cB1;
      const bool odd = g & 1;
      union { uint32_t u[4]; bf16x8 v; } uu;
      uu.u[0] = odd ? v0 : u0;  uu.u[1] = odd ? v1 : u1;
      uu.u[2] = odd ? u0 : v0;  uu.u[3] = odd ? u1 : v1;
      paf[qi] = uu.v;
    }

#pragma unroll
    for (int di = 0; di < 4; ++di) {
      bf16x8 vf = *(const bf16x8*)(VTb + (size_t)(di * 16 + lr) * S_ + kc + lk8);
      cacc[0][di] = __builtin_amdgcn_mfma_f32_16x16x32_bf16(paf[0], vf,
                                                            cacc[0][di], 0, 0, 0);
      cacc[1][di] = __builtin_amdgcn_mfma_f32_16x16x32_bf16(paf[1], vf,
                                                            cacc[1][di], 0, 0, 0);
    }
  }

  // zero-fill upper-triangular region (8 rows per wave)
  if (causal) {
    const int kz = qw + 32;
    const int c4 = (S_ - kz) >> 2;
#pragma unroll
    for (int rr = 0; rr < 8; ++rr) {
      const int r = wid * 8 + rr;
      float4* bp = (float4*)(arow + (size_t)(qw + r) * S_ + kz);
      for (int i = lane; i < c4; i += 64) bp[i] = make_float4(0.f, 0.f, 0.f, 0.f);
    }
  }

  // ---- reduce PV partials across waves ----
  __syncthreads();
  if (wid > 0) {
#pragma unroll
    for (int qi = 0; qi < 2; ++qi)
#pragma unroll
      for (int di = 0; di < 4; ++di)
#pragma unroll
        for (int j = 0; j < 4; ++j)
          red[wid - 1][lane][qi * 16 + di * 4 + j] = cacc[qi][di][j];
  }
  __syncthreads();
  if (wid == 0) {
#pragma unroll
    for (int w = 0; w < 3; ++w)
#pragma unroll
      for (int qi = 0; qi < 2; ++qi)
#pragma unroll
        for (int di = 0; di < 4; ++di)
#pragma unroll
          for (int j = 0; j < 4; ++j)
            cacc[qi][di][j] += red[w][lane][qi * 16 + di * 4 + j];

#pragma unroll
    for (int qi = 0; qi < 2; ++qi)
#pragma unroll
      for (int di = 0; di < 4; ++di)
#pragma unroll
        for (int j = 0; j < 4; ++j) {
          const int q = qw + qi * 16 + g4 + j;
          const int dk = di * 16 + lr;
          ctxb[((size_t)(b * S_ + q)) * D_ + hh * DK_ + dk] =
              f2b(cacc[qi][di][j]);
        }
  }
}

// ---------------------------------------------------------------------------
// k_oproj: out = ctxb(bf16) @ Wo^T + bo, f32 [M][D].  XCD-aware decode.
// ---------------------------------------------------------------------------
__global__ __launch_bounds__(256) void k_oproj(const short* __restrict__ Ab,
                                               const short* __restrict__ Wb,
                                               const float* __restrict__ bias,
                                               float* __restrict__ outf) {
  __shared__ short As[128][40];
  __shared__ short Bs[128][40];
  const int flat = blockIdx.x + 8 * blockIdx.y;     // 0..255
  const int xcd = flat & 7, slot = flat >> 3;
  const int m0 = (xcd + 8 * (slot & 3)) * 128;
  const int n0 = (slot >> 2) * 128;

  const int tid = threadIdx.x;
  const int wid = tid >> 6, lane = tid & 63;
  const int lr = lane & 15, lk8 = (lane >> 4) * 8;
  const int wm = (wid >> 1) * 64, wn = (wid & 1) * 64;

  f32x4 acc[4][4] = {};

  for (int kt = 0; kt < D_; kt += 32) {
#pragma unroll
    for (int i = 0; i < 2; ++i) {
      int li = tid + i * 256;
      int r = li >> 2, g = li & 3;
      int4 a = *(const int4*)(Ab + (size_t)(m0 + r) * D_ + kt + g * 8);
      *(int4*)&As[r][g * 8] = a;
      int4 w = *(const int4*)(Wb + (size_t)(n0 + r) * D_ + kt + g * 8);
      *(int4*)&Bs[r][g * 8] = w;
    }
    __syncthreads();

    bf16x8 af[4], bf[4];
#pragma unroll
    for (int x = 0; x < 4; ++x) {
      af[x] = *(const bf16x8*)&As[wm + x * 16 + lr][lk8];
      bf[x] = *(const bf16x8*)&Bs[wn + x * 16 + lr][lk8];
    }
#pragma unroll
    for (int mi = 0; mi < 4; ++mi)
#pragma unroll
      for (int ni = 0; ni < 4; ++ni)
        acc[mi][ni] = __builtin_amdgcn_mfma_f32_16x16x32_bf16(
            af[mi], bf[ni], acc[mi][ni], 0, 0, 0);
    __syncthreads();
  }

#pragma unroll
  for (int mi = 0; mi < 4; ++mi)
#pragma unroll
    for (int ni = 0; ni < 4; ++ni) {
      int n = n0 + wn + ni * 16 + lr;
      float bv = bias[n];
#pragma unroll
      for (int j = 0; j < 4; ++j) {
        int mm = m0 + wm + mi * 16 + (lane >> 4) * 4 + j;
        outf[(size_t)mm * D_ + n] = acc[mi][ni][j] + bv;
      }
    }
}

// ---------------------------------------------------------------------------
extern "C" void kernel_launch(void* const* d_in, const int* in_sizes, int n_in,
                              void* d_out, int out_size, void* d_ws,
                              size_t ws_size, hipStream_t stream) {
  (void)in_sizes; (void)n_in; (void)out_size; (void)ws_size;
  const float* X  = (const float*)d_in[0];
  const float* Wq = (const float*)d_in[1];
  const float* bq = (const float*)d_in[2];
  const float* Wk = (const float*)d_in[3];
  const float* bk = (const float*)d_in[4];
  const float* Wv = (const float*)d_in[5];
  const float* bv = (const float*)d_in[6];
  const float* Wo = (const float*)d_in[7];
  const float* bo = (const float*)d_in[8];
  const int* pad    = (const int*)d_in[9];
  const int* causal = (const int*)d_in[10];

  float* out   = (float*)d_out;                       // [B,S,D] f32
  float* alpha = out + (size_t)2 * S_ * D_;           // [B,H,S,S] f32

  short* wsb = (short*)d_ws;
  const size_t MM = (size_t)1 << 20;                  // 1M shorts
  short* Xb   = wsb;                                  // 4M
  short* Wqb  = wsb + 4 * MM;                         // 1M
  short* Wkb  = wsb + 5 * MM;
  short* Wvb  = wsb + 6 * MM;
  short* Wob  = wsb + 7 * MM;
  short* Qb   = wsb + 8 * MM;                         // 4M each
  short* Kb   = wsb + 12 * MM;
  short* Vb   = wsb + 16 * MM;
  short* VTb  = wsb + 20 * MM;
  short* ctxb = wsb + 24 * MM;                        // 4M
  float* padb = (float*)(wsb + 28 * MM);              // 4K f32

  dim3 blk(256);

  // X + weights -> bf16; padding bias
  k_cvt6<<<dim3(4096, 6), blk, 0, stream>>>(X, Wq, Wk, Wv, Wo, pad,
                                            Xb, Wqb, Wkb, Wvb, Wob, padb);

  // fused QKV projection (Q pre-scaled by 1/8), XCD-swizzled
  k_qkv<<<dim3(D_ / 128, M_ / 128, 3), blk, 0, stream>>>(
      Xb, Wqb, Wkb, Wvb, bq, bk, bv, Qb, Kb, Vb);

  // V -> V^T
  k_vt<<<dim3(S_ / 64, BH_), blk, 0, stream>>>(Vb, VTb);

  // flash attention + alpha write (XCD-aware 1D grid)
  k_apv<<<dim3(NT_ * BH_), blk, 0, stream>>>(Qb, Kb, VTb, padb, causal,
                                             alpha, ctxb);

  // output projection, XCD-swizzled
  k_oproj<<<dim3(D_ / 128, M_ / 128), blk, 0, stream>>>(ctxb, Wob, bo, out);
}

// Round 9
// 319.533 us; speedup vs baseline: 3.8398x; 1.0620x over previous
//
#include <hip/hip_runtime.h>
#include <cstdint>
#include <cstddef>

#define S_   2048
#define D_   1024
#define H_   16
#define DK_  64
#define BH_  32
#define M_   4096
#define NT_  64                      // 32-row q-tiles
#define NEG_INF_F (-3.4028234663852886e38f)

typedef short bf16x8 __attribute__((ext_vector_type(8)));
typedef float f32x4 __attribute__((ext_vector_type(4)));

__device__ __forceinline__ short f2b(float f) {
  union { float f; uint32_t u; } x; x.f = f;
  uint32_t r = (x.u + 0x7fffu + ((x.u >> 16) & 1u)) >> 16;  // RNE
  return (short)r;
}

// ---------------------------------------------------------------------------
// k_cvt6: f32 -> bf16 for X (job 0), 4 weights (jobs 1..4); job 5 builds the
// f32 padding-bias vector (pad==1 -> NEG_INF else 0).
// ---------------------------------------------------------------------------
__global__ __launch_bounds__(256) void k_cvt6(
    const float* __restrict__ X,  const float* __restrict__ Wq,
    const float* __restrict__ Wk, const float* __restrict__ Wv,
    const float* __restrict__ Wo, const int* __restrict__ pad,
    short* __restrict__ Xb,  short* __restrict__ Wqb,
    short* __restrict__ Wkb, short* __restrict__ Wvb,
    short* __restrict__ Wob, float* __restrict__ padb) {
  const int job = blockIdx.y;
  const int i = blockIdx.x * 256 + threadIdx.x;
  if (job == 5) {
    if (i < (2 * S_) / 4) {
      int4 p = ((const int4*)pad)[i];
      float4 o;
      o.x = p.x ? NEG_INF_F : 0.f;  o.y = p.y ? NEG_INF_F : 0.f;
      o.z = p.z ? NEG_INF_F : 0.f;  o.w = p.w ? NEG_INF_F : 0.f;
      ((float4*)padb)[i] = o;
    }
    return;
  }
  const float* src = job == 0 ? X : job == 1 ? Wq : job == 2 ? Wk
                   : job == 3 ? Wv : Wo;
  short* dst = job == 0 ? Xb : job == 1 ? Wqb : job == 2 ? Wkb
             : job == 3 ? Wvb : Wob;
  const int n4 = (job == 0) ? (M_ * D_ / 4) : (D_ * D_ / 4);
  if (i < n4) {
    float4 v = ((const float4*)src)[i];
    short4 s;
    s.x = f2b(v.x); s.y = f2b(v.y); s.z = f2b(v.z); s.w = f2b(v.w);
    ((short4*)dst)[i] = s;
  }
}

// ---------------------------------------------------------------------------
// k_qkv: fused QKV projection.  A = Xb bf16 [M][K]; z selects W/bias/dst.
// XCD-aware decode: xcd = flat%8 == m-panel%8 so each XCD reuses 4 X-panels.
// ---------------------------------------------------------------------------
__global__ __launch_bounds__(256) void k_qkv(
    const short* __restrict__ Ab,
    const short* __restrict__ W0, const short* __restrict__ W1,
    const short* __restrict__ W2,
    const float* __restrict__ b0, const float* __restrict__ b1,
    const float* __restrict__ b2,
    short* __restrict__ o0, short* __restrict__ o1, short* __restrict__ o2) {
  __shared__ short As[128][40];
  __shared__ short Bs[128][40];
  const int z = blockIdx.z;
  const short* Wb = z == 0 ? W0 : z == 1 ? W1 : W2;
  const float* bias = z == 0 ? b0 : z == 1 ? b1 : b2;
  short* outb = z == 0 ? o0 : z == 1 ? o1 : o2;
  const float oscale = (z == 0) ? 0.125f : 1.0f;

  const int flat = blockIdx.x + 8 * blockIdx.y;     // 0..255
  const int xcd = flat & 7, slot = flat >> 3;       // slot 0..31
  const int m0 = (xcd + 8 * (slot & 3)) * 128;      // 32 m-panels
  const int n0 = (slot >> 2) * 128;                 // 8 n-panels

  const int tid = threadIdx.x;
  const int wid = tid >> 6, lane = tid & 63;
  const int lr = lane & 15, lk8 = (lane >> 4) * 8;
  const int wm = (wid >> 1) * 64, wn = (wid & 1) * 64;

  f32x4 acc[4][4] = {};

  for (int kt = 0; kt < D_; kt += 32) {
#pragma unroll
    for (int i = 0; i < 2; ++i) {
      int li = tid + i * 256;
      int r = li >> 2, g = li & 3;
      int4 a = *(const int4*)(Ab + (size_t)(m0 + r) * D_ + kt + g * 8);
      *(int4*)&As[r][g * 8] = a;
      int4 w = *(const int4*)(Wb + (size_t)(n0 + r) * D_ + kt + g * 8);
      *(int4*)&Bs[r][g * 8] = w;
    }
    __syncthreads();

    bf16x8 af[4], bf[4];
#pragma unroll
    for (int x = 0; x < 4; ++x) {
      af[x] = *(const bf16x8*)&As[wm + x * 16 + lr][lk8];
      bf[x] = *(const bf16x8*)&Bs[wn + x * 16 + lr][lk8];
    }
#pragma unroll
    for (int mi = 0; mi < 4; ++mi)
#pragma unroll
      for (int ni = 0; ni < 4; ++ni)
        acc[mi][ni] = __builtin_amdgcn_mfma_f32_16x16x32_bf16(
            af[mi], bf[ni], acc[mi][ni], 0, 0, 0);
    __syncthreads();
  }

#pragma unroll
  for (int mi = 0; mi < 4; ++mi)
#pragma unroll
    for (int ni = 0; ni < 4; ++ni) {
      int n = n0 + wn + ni * 16 + lr;
      float bv = bias[n];
#pragma unroll
      for (int j = 0; j < 4; ++j) {
        int m = m0 + wm + mi * 16 + (lane >> 4) * 4 + j;
        float v = (acc[mi][ni][j] + bv) * oscale;
        int b = m >> 11, s = m & (S_ - 1);
        int h = n >> 6, dk = n & (DK_ - 1);
        outb[(((size_t)(b * H_ + h)) * S_ + s) * DK_ + dk] = f2b(v);
      }
    }
}

// ---------------------------------------------------------------------------
// k_vt: V [BH][S][DK] bf16 -> VT [BH][DK][S] bf16 (64x64 LDS tiles)
// ---------------------------------------------------------------------------
__global__ __launch_bounds__(256) void k_vt(const short* __restrict__ V,
                                            short* __restrict__ VT) {
  __shared__ short t[64][72];
  const int tid = threadIdx.x;
  const int bh = blockIdx.y, s0 = blockIdx.x * 64;
  const short* src = V + ((size_t)bh * S_ + s0) * DK_;
#pragma unroll
  for (int i = 0; i < 2; ++i) {
    int li = tid + i * 256;
    int r = li >> 3, g = li & 7;
    int4 v = *(const int4*)(src + r * DK_ + g * 8);
    *(int4*)&t[r][g * 8] = v;
  }
  __syncthreads();
  short* dst = VT + (size_t)bh * DK_ * S_ + s0;
#pragma unroll
  for (int i = 0; i < 2; ++i) {
    int li = tid + i * 256;
    int dkr = li >> 3, g = li & 7;
    short o[8];
#pragma unroll
    for (int j = 0; j < 8; ++j) o[j] = t[g * 8 + j][dkr];
    *(int4*)(dst + (size_t)dkr * S_ + g * 8) = *(int4*)o;
  }
}

// ---------------------------------------------------------------------------
// k_apv: swapped-QK^T flash attention + alpha write.  PAIRED TILES: each
// block processes q-tiles (pair, 63-pair) of one bh -> uniform 65 k-steps
// (causal) per block, 1024 blocks, 4 waves k-split.  XCD decode keeps 4 bh
// per XCD for K/VT L2 residency.
// ---------------------------------------------------------------------------
__global__ __launch_bounds__(256) void k_apv(const short* __restrict__ Q,
                                             const short* __restrict__ Kb,
                                             const short* __restrict__ VT,
                                             const float* __restrict__ padb,
                                             const int* __restrict__ causalp,
                                             float* __restrict__ alpha,
                                             short* __restrict__ ctxb) {
  __shared__ float red[3][64][32];   // PV partials (waves 1..3)
  __shared__ float ml[4][32][2];     // cross-wave (m,l)

  const int tid = threadIdx.x, wid = tid >> 6, lane = tid & 63;
  // XCD decode: 1024 blocks = 8 xcd x 128 slots
  const int id = blockIdx.x;
  const int xcd = id & 7, slot = id >> 3;           // slot 0..127
  const int bh = 8 * (slot & 3) + xcd;              // 4 bh per XCD
  const int pair = slot >> 2;                       // 0..31
  const int lr = lane & 15, lk8 = (lane >> 4) * 8;
  const int g = lane >> 4, g4 = g * 4;
  const int b = bh >> 4, hh = bh & (H_ - 1);
  const short* Qb = Q + (size_t)bh * S_ * DK_;
  const short* Kp = Kb + (size_t)bh * S_ * DK_;
  const short* VTb = VT + (size_t)bh * DK_ * S_;
  const float* pbias = padb + b * S_;
  float* arow = alpha + (size_t)bh * S_ * S_;

  const int causal = *causalp;

  for (int half = 0; half < 2; ++half) {
    const int tile = half == 0 ? (NT_ - 1 - pair) : pair;  // big tile first
    const int qw = tile * 32;
    const int nsteps = causal ? (tile + 1) : (S_ / 32);

    bf16x8 qf[2][2];
#pragma unroll
    for (int qi = 0; qi < 2; ++qi)
#pragma unroll
      for (int h = 0; h < 2; ++h)
        qf[qi][h] = *(const bf16x8*)(Qb + (size_t)(qw + qi * 16 + lr) * DK_ +
                                     h * 32 + lk8);

    // ---- pass 1: per-lane (m,l) over this wave's strided k-steps ----
    float m[2] = {-1e30f, -1e30f}, l[2] = {0.f, 0.f};

    for (int st = wid; st < nsteps; st += 4) {
      const int kc = st * 32;
      const bool diag = causal && (st == tile);
      float s[2][8];
#pragma unroll
      for (int h2 = 0; h2 < 2; ++h2) {
        const int kcc = kc + h2 * 16;
        bf16x8 kf0 = *(const bf16x8*)(Kp + (size_t)(kcc + lr) * DK_ + lk8);
        bf16x8 kf1 = *(const bf16x8*)(Kp + (size_t)(kcc + lr) * DK_ + 32 + lk8);
        float4 pb = *(const float4*)(pbias + kcc + g4);
#pragma unroll
        for (int qi = 0; qi < 2; ++qi) {
          f32x4 z = {0.f, 0.f, 0.f, 0.f};
          z = __builtin_amdgcn_mfma_f32_16x16x32_bf16(kf0, qf[qi][0], z, 0, 0, 0);
          z = __builtin_amdgcn_mfma_f32_16x16x32_bf16(kf1, qf[qi][1], z, 0, 0, 0);
          const int q = qw + qi * 16 + lr;
#pragma unroll
          for (int j = 0; j < 4; ++j) {
            float sv = z[j] + ((const float*)&pb)[j];
            if (diag && (kcc + g4 + j > q)) sv = NEG_INF_F;
            s[qi][h2 * 4 + j] = sv;
          }
        }
      }
#pragma unroll
      for (int qi = 0; qi < 2; ++qi) {
        float pm = fmaxf(fmaxf(fmaxf(s[qi][0], s[qi][1]), fmaxf(s[qi][2], s[qi][3])),
                         fmaxf(fmaxf(s[qi][4], s[qi][5]), fmaxf(s[qi][6], s[qi][7])));
        const float mn = fmaxf(m[qi], pm);
        float sum = 0.f;
#pragma unroll
        for (int jj = 0; jj < 8; ++jj) sum += __expf(s[qi][jj] - mn);
        l[qi] = l[qi] * __expf(m[qi] - mn) + sum;
        m[qi] = mn;
      }
    }

    // merge across the 4 k-groups (lanes lr, 16+lr, 32+lr, 48+lr)
#pragma unroll
    for (int off = 16; off <= 32; off <<= 1) {
#pragma unroll
      for (int qi = 0; qi < 2; ++qi) {
        const float mo = __shfl_xor(m[qi], off);
        const float lo = __shfl_xor(l[qi], off);
        const float mn = fmaxf(m[qi], mo);
        l[qi] = l[qi] * __expf(m[qi] - mn) + lo * __expf(mo - mn);
        m[qi] = mn;
      }
    }
    if (g == 0) {
      ml[wid][lr][0] = m[0];      ml[wid][lr][1] = l[0];
      ml[wid][16 + lr][0] = m[1]; ml[wid][16 + lr][1] = l[1];
    }
    __syncthreads();
    float li[2];
#pragma unroll
    for (int qi = 0; qi < 2; ++qi) {
      const int row = qi * 16 + lr;
      float mf = ml[0][row][0], lf = ml[0][row][1];
#pragma unroll
      for (int w = 1; w < 4; ++w) {
        const float mo = ml[w][row][0], lo = ml[w][row][1];
        const float mn = fmaxf(mf, mo);
        lf = lf * __expf(mf - mn) + lo * __expf(mo - mn);
        mf = mn;
      }
      m[qi] = mf;
      li[qi] = 1.0f / lf;
    }

    // ---- pass 2: alpha + partial PV over this wave's k-steps ----
    f32x4 cacc[2][4] = {};

    for (int st = wid; st < nsteps; st += 4) {
      const int kc = st * 32;
      const bool diag = causal && (st == tile);
      uint32_t pk[2][2][2];
#pragma unroll
      for (int h2 = 0; h2 < 2; ++h2) {
        const int kcc = kc + h2 * 16;
        bf16x8 kf0 = *(const bf16x8*)(Kp + (size_t)(kcc + lr) * DK_ + lk8);
        bf16x8 kf1 = *(const bf16x8*)(Kp + (size_t)(kcc + lr) * DK_ + 32 + lk8);
        float4 pb = *(const float4*)(pbias + kcc + g4);
#pragma unroll
        for (int qi = 0; qi < 2; ++qi) {
          f32x4 z = {0.f, 0.f, 0.f, 0.f};
          z = __builtin_amdgcn_mfma_f32_16x16x32_bf16(kf0, qf[qi][0], z, 0, 0, 0);
          z = __builtin_amdgcn_mfma_f32_16x16x32_bf16(kf1, qf[qi][1], z, 0, 0, 0);
          const int q = qw + qi * 16 + lr;
          float a[4];
#pragma unroll
          for (int j = 0; j < 4; ++j) {
            float sv = z[j] + ((const float*)&pb)[j];
            if (diag && (kcc + g4 + j > q)) sv = NEG_INF_F;
            a[j] = __expf(sv - m[qi]) * li[qi];
          }
          *(float4*)(arow + (size_t)q * S_ + kcc + g4) =
              make_float4(a[0], a[1], a[2], a[3]);
          asm volatile("v_cvt_pk_bf16_f32 %0, %1, %2"
                       : "=v"(pk[qi][h2][0]) : "v"(a[0]), "v"(a[1]));
          asm volatile("v_cvt_pk_bf16_f32 %0, %1, %2"
                       : "=v"(pk[qi][h2][1]) : "v"(a[2]), "v"(a[3]));
        }
      }

      // redistribute P to MFMA A-frags: lane g needs X(h=g>>1, 2(g&1)..+1)
      bf16x8 paf[2];
#pragma unroll
      for (int qi = 0; qi < 2; ++qi) {
        const uint32_t x00 = pk[qi][0][0], x01 = pk[qi][0][1];
        const uint32_t x10 = pk[qi][1][0], x11 = pk[qi][1][1];
        const uint32_t y00 = __shfl_xor((int)x00, 32);
        const uint32_t y01 = __shfl_xor((int)x01, 32);
        const uint32_t y10 = __shfl_xor((int)x10, 32);
        const uint32_t y11 = __shfl_xor((int)x11, 32);
        const bool hi2 = (g >= 2);
        const uint32_t a0 = hi2 ? x10 : x00, a1 = hi2 ? x11 : x01;
        const uint32_t b0 = hi2 ? y10 : y00, b1 = hi2 ? y11 : y01;
        const uint32_t cA0 = __shfl_xor((int)a0, 16);
        const uint32_t cA1 = __shfl_xor((int)a1, 16);
        const uint32_t cB0 = __shfl_xor((int)b0, 16);
        const uint32_t cB1 = __shfl_xor((int)b1, 16);
        const bool sel_a = (g == 0) || (g == 3);
        const uint32_t u0 = sel_a ? a0 : b0, u1 = sel_a ? a1 : b1;
        const uint32_t v0 = sel_a ? cA0 : cB0, v1 = sel_a ? cA1 : cB1;
        const bool odd = g & 1;
        union { uint32_t u[4]; bf16x8 v; } uu;
        uu.u[0] = odd ? v0 : u0;  uu.u[1] = odd ? v1 : u1;
        uu.u[2] = odd ? u0 : v0;  uu.u[3] = odd ? u1 : v1;
        paf[qi] = uu.v;
      }

#pragma unroll
      for (int di = 0; di < 4; ++di) {
        bf16x8 vf = *(const bf16x8*)(VTb + (size_t)(di * 16 + lr) * S_ + kc + lk8);
        cacc[0][di] = __builtin_amdgcn_mfma_f32_16x16x32_bf16(paf[0], vf,
                                                              cacc[0][di], 0, 0, 0);
        cacc[1][di] = __builtin_amdgcn_mfma_f32_16x16x32_bf16(paf[1], vf,
                                                              cacc[1][di], 0, 0, 0);
      }
    }

    // zero-fill upper-triangular region (8 rows per wave)
    if (causal) {
      const int kz = qw + 32;
      const int c4 = (S_ - kz) >> 2;
#pragma unroll
      for (int rr = 0; rr < 8; ++rr) {
        const int r = wid * 8 + rr;
        float4* bp = (float4*)(arow + (size_t)(qw + r) * S_ + kz);
        for (int i = lane; i < c4; i += 64) bp[i] = make_float4(0.f, 0.f, 0.f, 0.f);
      }
    }

    // ---- reduce PV partials across waves ----
    __syncthreads();
    if (wid > 0) {
#pragma unroll
      for (int qi = 0; qi < 2; ++qi)
#pragma unroll
        for (int di = 0; di < 4; ++di)
#pragma unroll
          for (int j = 0; j < 4; ++j)
            red[wid - 1][lane][qi * 16 + di * 4 + j] = cacc[qi][di][j];
    }
    __syncthreads();
    if (wid == 0) {
#pragma unroll
      for (int w = 0; w < 3; ++w)
#pragma unroll
        for (int qi = 0; qi < 2; ++qi)
#pragma unroll
          for (int di = 0; di < 4; ++di)
#pragma unroll
            for (int j = 0; j < 4; ++j)
              cacc[qi][di][j] += red[w][lane][qi * 16 + di * 4 + j];

#pragma unroll
      for (int qi = 0; qi < 2; ++qi)
#pragma unroll
        for (int di = 0; di < 4; ++di)
#pragma unroll
          for (int j = 0; j < 4; ++j) {
            const int q = qw + qi * 16 + g4 + j;
            const int dk = di * 16 + lr;
            ctxb[((size_t)(b * S_ + q)) * D_ + hh * DK_ + dk] =
                f2b(cacc[qi][di][j]);
          }
    }
    __syncthreads();   // fence LDS reuse before next half
  }
}

// ---------------------------------------------------------------------------
// k_oproj: out = ctxb(bf16) @ Wo^T + bo, f32 [M][D].  XCD-aware decode.
// ---------------------------------------------------------------------------
__global__ __launch_bounds__(256) void k_oproj(const short* __restrict__ Ab,
                                               const short* __restrict__ Wb,
                                               const float* __restrict__ bias,
                                               float* __restrict__ outf) {
  __shared__ short As[128][40];
  __shared__ short Bs[128][40];
  const int flat = blockIdx.x + 8 * blockIdx.y;     // 0..255
  const int xcd = flat & 7, slot = flat >> 3;
  const int m0 = (xcd + 8 * (slot & 3)) * 128;
  const int n0 = (slot >> 2) * 128;

  const int tid = threadIdx.x;
  const int wid = tid >> 6, lane = tid & 63;
  const int lr = lane & 15, lk8 = (lane >> 4) * 8;
  const int wm = (wid >> 1) * 64, wn = (wid & 1) * 64;

  f32x4 acc[4][4] = {};

  for (int kt = 0; kt < D_; kt += 32) {
#pragma unroll
    for (int i = 0; i < 2; ++i) {
      int li = tid + i * 256;
      int r = li >> 2, g = li & 3;
      int4 a = *(const int4*)(Ab + (size_t)(m0 + r) * D_ + kt + g * 8);
      *(int4*)&As[r][g * 8] = a;
      int4 w = *(const int4*)(Wb + (size_t)(n0 + r) * D_ + kt + g * 8);
      *(int4*)&Bs[r][g * 8] = w;
    }
    __syncthreads();

    bf16x8 af[4], bf[4];
#pragma unroll
    for (int x = 0; x < 4; ++x) {
      af[x] = *(const bf16x8*)&As[wm + x * 16 + lr][lk8];
      bf[x] = *(const bf16x8*)&Bs[wn + x * 16 + lr][lk8];
    }
#pragma unroll
    for (int mi = 0; mi < 4; ++mi)
#pragma unroll
      for (int ni = 0; ni < 4; ++ni)
        acc[mi][ni] = __builtin_amdgcn_mfma_f32_16x16x32_bf16(
            af[mi], bf[ni], acc[mi][ni], 0, 0, 0);
    __syncthreads();
  }

#pragma unroll
  for (int mi = 0; mi < 4; ++mi)
#pragma unroll
    for (int ni = 0; ni < 4; ++ni) {
      int n = n0 + wn + ni * 16 + lr;
      float bv = bias[n];
#pragma unroll
      for (int j = 0; j < 4; ++j) {
        int mm = m0 + wm + mi * 16 + (lane >> 4) * 4 + j;
        outf[(size_t)mm * D_ + n] = acc[mi][ni][j] + bv;
      }
    }
}

// ---------------------------------------------------------------------------
extern "C" void kernel_launch(void* const* d_in, const int* in_sizes, int n_in,
                              void* d_out, int out_size, void* d_ws,
                              size_t ws_size, hipStream_t stream) {
  (void)in_sizes; (void)n_in; (void)out_size; (void)ws_size;
  const float* X  = (const float*)d_in[0];
  const float* Wq = (const float*)d_in[1];
  const float* bq = (const float*)d_in[2];
  const float* Wk = (const float*)d_in[3];
  const float* bk = (const float*)d_in[4];
  const float* Wv = (const float*)d_in[5];
  const float* bv = (const float*)d_in[6];
  const float* Wo = (const float*)d_in[7];
  const float* bo = (const float*)d_in[8];
  const int* pad    = (const int*)d_in[9];
  const int* causal = (const int*)d_in[10];

  float* out   = (float*)d_out;                       // [B,S,D] f32
  float* alpha = out + (size_t)2 * S_ * D_;           // [B,H,S,S] f32

  short* wsb = (short*)d_ws;
  const size_t MM = (size_t)1 << 20;                  // 1M shorts
  short* Xb   = wsb;                                  // 4M
  short* Wqb  = wsb + 4 * MM;                         // 1M
  short* Wkb  = wsb + 5 * MM;
  short* Wvb  = wsb + 6 * MM;
  short* Wob  = wsb + 7 * MM;
  short* Qb   = wsb + 8 * MM;                         // 4M each
  short* Kb   = wsb + 12 * MM;
  short* Vb   = wsb + 16 * MM;
  short* VTb  = wsb + 20 * MM;
  short* ctxb = wsb + 24 * MM;                        // 4M
  float* padb = (float*)(wsb + 28 * MM);              // 4K f32

  dim3 blk(256);

  // X + weights -> bf16; padding bias
  k_cvt6<<<dim3(4096, 6), blk, 0, stream>>>(X, Wq, Wk, Wv, Wo, pad,
                                            Xb, Wqb, Wkb, Wvb, Wob, padb);

  // fused QKV projection (Q pre-scaled by 1/8), XCD-swizzled
  k_qkv<<<dim3(D_ / 128, M_ / 128, 3), blk, 0, stream>>>(
      Xb, Wqb, Wkb, Wvb, bq, bk, bv, Qb, Kb, Vb);

  // V -> V^T
  k_vt<<<dim3(S_ / 64, BH_), blk, 0, stream>>>(Vb, VTb);

  // flash attention + alpha write (paired tiles, uniform work, XCD-aware)
  k_apv<<<dim3(NT_ * BH_ / 2), blk, 0, stream>>>(Qb, Kb, VTb, padb, causal,
                                                 alpha, ctxb);

  // output projection, XCD-swizzled
  k_oproj<<<dim3(D_ / 128, M_ / 128), blk, 0, stream>>>(ctxb, Wob, bo, out);
}

// Round 10
// 287.743 us; speedup vs baseline: 4.2641x; 1.1105x over previous
//
#include <hip/hip_runtime.h>
#include <cstdint>
#include <cstddef>

#define S_   2048
#define D_   1024
#define H_   16
#define DK_  64
#define BH_  32
#define M_   4096
#define NT_  64                      // 32-row q-tiles
#define NEG_INF_F (-3.4028234663852886e38f)
#define QSCALE_F 0.1803368801111137f   // 0.125 * log2(e)

typedef short bf16x8 __attribute__((ext_vector_type(8)));
typedef float f32x4 __attribute__((ext_vector_type(4)));

__device__ __forceinline__ short f2b(float f) {
  union { float f; uint32_t u; } x; x.f = f;
  uint32_t r = (x.u + 0x7fffu + ((x.u >> 16) & 1u)) >> 16;  // RNE
  return (short)r;
}

// ---------------------------------------------------------------------------
// k_cvt6: f32 -> bf16 for X (job 0), 4 weights (jobs 1..4); job 5 builds the
// f32 padding-bias vector (pad==1 -> NEG_INF else 0; log2-domain safe).
// ---------------------------------------------------------------------------
__global__ __launch_bounds__(256) void k_cvt6(
    const float* __restrict__ X,  const float* __restrict__ Wq,
    const float* __restrict__ Wk, const float* __restrict__ Wv,
    const float* __restrict__ Wo, const int* __restrict__ pad,
    short* __restrict__ Xb,  short* __restrict__ Wqb,
    short* __restrict__ Wkb, short* __restrict__ Wvb,
    short* __restrict__ Wob, float* __restrict__ padb) {
  const int job = blockIdx.y;
  const int i = blockIdx.x * 256 + threadIdx.x;
  if (job == 5) {
    if (i < (2 * S_) / 4) {
      int4 p = ((const int4*)pad)[i];
      float4 o;
      o.x = p.x ? NEG_INF_F : 0.f;  o.y = p.y ? NEG_INF_F : 0.f;
      o.z = p.z ? NEG_INF_F : 0.f;  o.w = p.w ? NEG_INF_F : 0.f;
      ((float4*)padb)[i] = o;
    }
    return;
  }
  const float* src = job == 0 ? X : job == 1 ? Wq : job == 2 ? Wk
                   : job == 3 ? Wv : Wo;
  short* dst = job == 0 ? Xb : job == 1 ? Wqb : job == 2 ? Wkb
             : job == 3 ? Wvb : Wob;
  const int n4 = (job == 0) ? (M_ * D_ / 4) : (D_ * D_ / 4);
  if (i < n4) {
    float4 v = ((const float4*)src)[i];
    short4 s;
    s.x = f2b(v.x); s.y = f2b(v.y); s.z = f2b(v.z); s.w = f2b(v.w);
    ((short4*)dst)[i] = s;
  }
}

// ---------------------------------------------------------------------------
// k_qkv: fused QKV projection.  z=0: Q (scaled by 0.125*log2e, head layout);
// z=1: K (head layout); z=2: V written DIRECTLY TRANSPOSED as VT [bh][dk][s].
// XCD-aware decode: xcd = flat%8 == m-panel%8 so each XCD reuses 4 X-panels.
// ---------------------------------------------------------------------------
__global__ __launch_bounds__(256) void k_qkv(
    const short* __restrict__ Ab,
    const short* __restrict__ W0, const short* __restrict__ W1,
    const short* __restrict__ W2,
    const float* __restrict__ b0, const float* __restrict__ b1,
    const float* __restrict__ b2,
    short* __restrict__ o0, short* __restrict__ o1, short* __restrict__ o2) {
  __shared__ short As[128][40];
  __shared__ short Bs[128][40];
  const int z = blockIdx.z;
  const short* Wb = z == 0 ? W0 : z == 1 ? W1 : W2;
  const float* bias = z == 0 ? b0 : z == 1 ? b1 : b2;
  const float oscale = (z == 0) ? QSCALE_F : 1.0f;

  const int flat = blockIdx.x + 8 * blockIdx.y;     // 0..255
  const int xcd = flat & 7, slot = flat >> 3;       // slot 0..31
  const int m0 = (xcd + 8 * (slot & 3)) * 128;      // 32 m-panels
  const int n0 = (slot >> 2) * 128;                 // 8 n-panels

  const int tid = threadIdx.x;
  const int wid = tid >> 6, lane = tid & 63;
  const int lr = lane & 15, lk8 = (lane >> 4) * 8;
  const int g4 = (lane >> 4) * 4;
  const int wm = (wid >> 1) * 64, wn = (wid & 1) * 64;

  f32x4 acc[4][4] = {};

  for (int kt = 0; kt < D_; kt += 32) {
#pragma unroll
    for (int i = 0; i < 2; ++i) {
      int li = tid + i * 256;
      int r = li >> 2, gg = li & 3;
      int4 a = *(const int4*)(Ab + (size_t)(m0 + r) * D_ + kt + gg * 8);
      *(int4*)&As[r][gg * 8] = a;
      int4 w = *(const int4*)(Wb + (size_t)(n0 + r) * D_ + kt + gg * 8);
      *(int4*)&Bs[r][gg * 8] = w;
    }
    __syncthreads();

    bf16x8 af[4], bf[4];
#pragma unroll
    for (int x = 0; x < 4; ++x) {
      af[x] = *(const bf16x8*)&As[wm + x * 16 + lr][lk8];
      bf[x] = *(const bf16x8*)&Bs[wn + x * 16 + lr][lk8];
    }
#pragma unroll
    for (int mi = 0; mi < 4; ++mi)
#pragma unroll
      for (int ni = 0; ni < 4; ++ni)
        acc[mi][ni] = __builtin_amdgcn_mfma_f32_16x16x32_bf16(
            af[mi], bf[ni], acc[mi][ni], 0, 0, 0);
    __syncthreads();
  }

#pragma unroll
  for (int mi = 0; mi < 4; ++mi)
#pragma unroll
    for (int ni = 0; ni < 4; ++ni) {
      int n = n0 + wn + ni * 16 + lr;
      float bv = bias[n];
      if (z == 2) {
        // VT layout [bh][dk][s]: 4 consecutive s per lane -> short4
        int mbase = m0 + wm + mi * 16 + g4;
        int bb = mbase >> 11, s = mbase & (S_ - 1);
        int h = n >> 6, dk = n & (DK_ - 1);
        short4 o;
        o.x = f2b(acc[mi][ni][0] + bv);
        o.y = f2b(acc[mi][ni][1] + bv);
        o.z = f2b(acc[mi][ni][2] + bv);
        o.w = f2b(acc[mi][ni][3] + bv);
        *(short4*)(o2 + (((size_t)(bb * H_ + h)) * DK_ + dk) * S_ + s) = o;
      } else {
        short* outb = (z == 0) ? o0 : o1;
#pragma unroll
        for (int j = 0; j < 4; ++j) {
          int m = m0 + wm + mi * 16 + g4 + j;
          float v = (acc[mi][ni][j] + bv) * oscale;
          int bb = m >> 11, s = m & (S_ - 1);
          int h = n >> 6, dk = n & (DK_ - 1);
          outb[(((size_t)(bb * H_ + h)) * S_ + s) * DK_ + dk] = f2b(v);
        }
      }
    }
}

// ---------------------------------------------------------------------------
// k_apv: swapped-QK^T flash attention + alpha write.  Paired tiles (uniform
// work), 4 waves k-split, XCD-pinned bh.  64-COLUMN k-steps (4x16 slices):
// half the per-step serial chains, 2x ILP.  log2-domain scores (Q pre-scaled
// by 0.125*log2e) -> exp2f.  Odd 32-col tails handled by the causal mask
// (masked cols write alpha=0, matching the zero-fill).
// ---------------------------------------------------------------------------
__global__ __launch_bounds__(256) void k_apv(const short* __restrict__ Q,
                                             const short* __restrict__ Kb,
                                             const short* __restrict__ VT,
                                             const float* __restrict__ padb,
                                             const int* __restrict__ causalp,
                                             float* __restrict__ alpha,
                                             short* __restrict__ ctxb) {
  __shared__ float red[3][64][32];   // PV partials (waves 1..3)
  __shared__ float ml[4][32][2];     // cross-wave (m,l)

  const int tid = threadIdx.x, wid = tid >> 6, lane = tid & 63;
  const int id = blockIdx.x;                        // 1024 blocks
  const int xcd = id & 7, slot = id >> 3;           // slot 0..127
  const int bh = 8 * (slot & 3) + xcd;              // 4 bh per XCD
  const int pair = slot >> 2;                       // 0..31
  const int lr = lane & 15, lk8 = (lane >> 4) * 8;
  const int g = lane >> 4, g4 = g * 4;
  const int b = bh >> 4, hh = bh & (H_ - 1);
  const short* Qb = Q + (size_t)bh * S_ * DK_;
  const short* Kp = Kb + (size_t)bh * S_ * DK_;
  const short* VTb = VT + (size_t)bh * DK_ * S_;
  const float* pbias = padb + b * S_;
  float* arow = alpha + (size_t)bh * S_ * S_;

  const int causal = *causalp;

  for (int half = 0; half < 2; ++half) {
    const int tile = half == 0 ? (NT_ - 1 - pair) : pair;  // big tile first
    const int qw = tile * 32;
    const int nsteps = causal ? (tile + 1) : (S_ / 32);    // 32-col units
    const int N = (nsteps + 1) >> 1;                       // 64-col steps

    bf16x8 qf[2][2];
#pragma unroll
    for (int qi = 0; qi < 2; ++qi)
#pragma unroll
      for (int h = 0; h < 2; ++h)
        qf[qi][h] = *(const bf16x8*)(Qb + (size_t)(qw + qi * 16 + lr) * DK_ +
                                     h * 32 + lk8);

    // ---- pass 1: per-lane (m,l) over this wave's strided 64-col steps ----
    float m[2] = {-1e30f, -1e30f}, l[2] = {0.f, 0.f};

    for (int st = wid; st < N; st += 4) {
      const int kc = st * 64;
      const bool diag = causal && (2 * st + 1 >= tile);
      float s[2][16];
#pragma unroll
      for (int h2 = 0; h2 < 4; ++h2) {
        const int kcc = kc + h2 * 16;
        bf16x8 kf0 = *(const bf16x8*)(Kp + (size_t)(kcc + lr) * DK_ + lk8);
        bf16x8 kf1 = *(const bf16x8*)(Kp + (size_t)(kcc + lr) * DK_ + 32 + lk8);
        float4 pb = *(const float4*)(pbias + kcc + g4);
#pragma unroll
        for (int qi = 0; qi < 2; ++qi) {
          f32x4 z = {0.f, 0.f, 0.f, 0.f};
          z = __builtin_amdgcn_mfma_f32_16x16x32_bf16(kf0, qf[qi][0], z, 0, 0, 0);
          z = __builtin_amdgcn_mfma_f32_16x16x32_bf16(kf1, qf[qi][1], z, 0, 0, 0);
          const int q = qw + qi * 16 + lr;
#pragma unroll
          for (int j = 0; j < 4; ++j) {
            float sv = z[j] + ((const float*)&pb)[j];
            if (diag && (kcc + g4 + j > q)) sv = NEG_INF_F;
            s[qi][h2 * 4 + j] = sv;
          }
        }
      }
#pragma unroll
      for (int qi = 0; qi < 2; ++qi) {
        float p0 = fmaxf(fmaxf(s[qi][0], s[qi][1]), fmaxf(s[qi][2], s[qi][3]));
        float p1 = fmaxf(fmaxf(s[qi][4], s[qi][5]), fmaxf(s[qi][6], s[qi][7]));
        float p2 = fmaxf(fmaxf(s[qi][8], s[qi][9]), fmaxf(s[qi][10], s[qi][11]));
        float p3 = fmaxf(fmaxf(s[qi][12], s[qi][13]), fmaxf(s[qi][14], s[qi][15]));
        const float pm = fmaxf(fmaxf(p0, p1), fmaxf(p2, p3));
        const float mn = fmaxf(m[qi], pm);
        float sum = 0.f;
#pragma unroll
        for (int jj = 0; jj < 16; ++jj) sum += exp2f(s[qi][jj] - mn);
        l[qi] = l[qi] * exp2f(m[qi] - mn) + sum;
        m[qi] = mn;
      }
    }

    // merge across the 4 k-groups (lanes lr, 16+lr, 32+lr, 48+lr)
#pragma unroll
    for (int off = 16; off <= 32; off <<= 1) {
#pragma unroll
      for (int qi = 0; qi < 2; ++qi) {
        const float mo = __shfl_xor(m[qi], off);
        const float lo = __shfl_xor(l[qi], off);
        const float mn = fmaxf(m[qi], mo);
        l[qi] = l[qi] * exp2f(m[qi] - mn) + lo * exp2f(mo - mn);
        m[qi] = mn;
      }
    }
    if (g == 0) {
      ml[wid][lr][0] = m[0];      ml[wid][lr][1] = l[0];
      ml[wid][16 + lr][0] = m[1]; ml[wid][16 + lr][1] = l[1];
    }
    __syncthreads();
    float li[2];
#pragma unroll
    for (int qi = 0; qi < 2; ++qi) {
      const int row = qi * 16 + lr;
      float mf = ml[0][row][0], lf = ml[0][row][1];
#pragma unroll
      for (int w = 1; w < 4; ++w) {
        const float mo = ml[w][row][0], lo = ml[w][row][1];
        const float mn = fmaxf(mf, mo);
        lf = lf * exp2f(mf - mn) + lo * exp2f(mo - mn);
        mf = mn;
      }
      m[qi] = mf;
      li[qi] = 1.0f / lf;
    }

    // ---- pass 2: alpha + partial PV over this wave's 64-col steps ----
    f32x4 cacc[2][4] = {};

    for (int st = wid; st < N; st += 4) {
      const int kc = st * 64;
      const bool diag = causal && (2 * st + 1 >= tile);
      uint32_t pk[2][4][2];
#pragma unroll
      for (int h2 = 0; h2 < 4; ++h2) {
        const int kcc = kc + h2 * 16;
        bf16x8 kf0 = *(const bf16x8*)(Kp + (size_t)(kcc + lr) * DK_ + lk8);
        bf16x8 kf1 = *(const bf16x8*)(Kp + (size_t)(kcc + lr) * DK_ + 32 + lk8);
        float4 pb = *(const float4*)(pbias + kcc + g4);
#pragma unroll
        for (int qi = 0; qi < 2; ++qi) {
          f32x4 z = {0.f, 0.f, 0.f, 0.f};
          z = __builtin_amdgcn_mfma_f32_16x16x32_bf16(kf0, qf[qi][0], z, 0, 0, 0);
          z = __builtin_amdgcn_mfma_f32_16x16x32_bf16(kf1, qf[qi][1], z, 0, 0, 0);
          const int q = qw + qi * 16 + lr;
          float a[4];
#pragma unroll
          for (int j = 0; j < 4; ++j) {
            float sv = z[j] + ((const float*)&pb)[j];
            if (diag && (kcc + g4 + j > q)) sv = NEG_INF_F;
            a[j] = exp2f(sv - m[qi]) * li[qi];
          }
          *(float4*)(arow + (size_t)q * S_ + kcc + g4) =
              make_float4(a[0], a[1], a[2], a[3]);
          asm volatile("v_cvt_pk_bf16_f32 %0, %1, %2"
                       : "=v"(pk[qi][h2][0]) : "v"(a[0]), "v"(a[1]));
          asm volatile("v_cvt_pk_bf16_f32 %0, %1, %2"
                       : "=v"(pk[qi][h2][1]) : "v"(a[2]), "v"(a[3]));
        }
      }

      // two 32-col PV groups; per group redistribute P to MFMA A-frags
#pragma unroll
      for (int c = 0; c < 2; ++c) {
        bf16x8 paf[2];
#pragma unroll
        for (int qi = 0; qi < 2; ++qi) {
          const uint32_t x00 = pk[qi][2 * c][0], x01 = pk[qi][2 * c][1];
          const uint32_t x10 = pk[qi][2 * c + 1][0], x11 = pk[qi][2 * c + 1][1];
          const uint32_t y00 = __shfl_xor((int)x00, 32);
          const uint32_t y01 = __shfl_xor((int)x01, 32);
          const uint32_t y10 = __shfl_xor((int)x10, 32);
          const uint32_t y11 = __shfl_xor((int)x11, 32);
          const bool hi2 = (g >= 2);
          const uint32_t a0 = hi2 ? x10 : x00, a1 = hi2 ? x11 : x01;
          const uint32_t b0 = hi2 ? y10 : y00, b1 = hi2 ? y11 : y01;
          const uint32_t cA0 = __shfl_xor((int)a0, 16);
          const uint32_t cA1 = __shfl_xor((int)a1, 16);
          const uint32_t cB0 = __shfl_xor((int)b0, 16);
          const uint32_t cB1 = __shfl_xor((int)b1, 16);
          const bool sel_a = (g == 0) || (g == 3);
          const uint32_t u0 = sel_a ? a0 : b0, u1 = sel_a ? a1 : b1;
          const uint32_t v0 = sel_a ? cA0 : cB0, v1 = sel_a ? cA1 : cB1;
          const bool odd = g & 1;
          union { uint32_t u[4]; bf16x8 v; } uu;
          uu.u[0] = odd ? v0 : u0;  uu.u[1] = odd ? v1 : u1;
          uu.u[2] = odd ? u0 : v0;  uu.u[3] = odd ? u1 : v1;
          paf[qi] = uu.v;
        }
        const int kcc2 = kc + c * 32;
#pragma unroll
        for (int di = 0; di < 4; ++di) {
          bf16x8 vf =
              *(const bf16x8*)(VTb + (size_t)(di * 16 + lr) * S_ + kcc2 + lk8);
          cacc[0][di] = __builtin_amdgcn_mfma_f32_16x16x32_bf16(
              paf[0], vf, cacc[0][di], 0, 0, 0);
          cacc[1][di] = __builtin_amdgcn_mfma_f32_16x16x32_bf16(
              paf[1], vf, cacc[1][di], 0, 0, 0);
        }
      }
    }

    // zero-fill upper-triangular region (8 rows per wave)
    if (causal) {
      const int kz = qw + 32;
      const int c4 = (S_ - kz) >> 2;
#pragma unroll
      for (int rr = 0; rr < 8; ++rr) {
        const int r = wid * 8 + rr;
        float4* bp = (float4*)(arow + (size_t)(qw + r) * S_ + kz);
        for (int i = lane; i < c4; i += 64) bp[i] = make_float4(0.f, 0.f, 0.f, 0.f);
      }
    }

    // ---- reduce PV partials across waves ----
    __syncthreads();
    if (wid > 0) {
#pragma unroll
      for (int qi = 0; qi < 2; ++qi)
#pragma unroll
        for (int di = 0; di < 4; ++di)
#pragma unroll
          for (int j = 0; j < 4; ++j)
            red[wid - 1][lane][qi * 16 + di * 4 + j] = cacc[qi][di][j];
    }
    __syncthreads();
    if (wid == 0) {
#pragma unroll
      for (int w = 0; w < 3; ++w)
#pragma unroll
        for (int qi = 0; qi < 2; ++qi)
#pragma unroll
          for (int di = 0; di < 4; ++di)
#pragma unroll
            for (int j = 0; j < 4; ++j)
              cacc[qi][di][j] += red[w][lane][qi * 16 + di * 4 + j];

#pragma unroll
      for (int qi = 0; qi < 2; ++qi)
#pragma unroll
        for (int di = 0; di < 4; ++di)
#pragma unroll
          for (int j = 0; j < 4; ++j) {
            const int q = qw + qi * 16 + g4 + j;
            const int dk = di * 16 + lr;
            ctxb[((size_t)(b * S_ + q)) * D_ + hh * DK_ + dk] =
                f2b(cacc[qi][di][j]);
          }
    }
    __syncthreads();   // fence LDS reuse before next half
  }
}

// ---------------------------------------------------------------------------
// k_oproj: out = ctxb(bf16) @ Wo^T + bo, f32 [M][D].  XCD-aware decode.
// ---------------------------------------------------------------------------
__global__ __launch_bounds__(256) void k_oproj(const short* __restrict__ Ab,
                                               const short* __restrict__ Wb,
                                               const float* __restrict__ bias,
                                               float* __restrict__ outf) {
  __shared__ short As[128][40];
  __shared__ short Bs[128][40];
  const int flat = blockIdx.x + 8 * blockIdx.y;     // 0..255
  const int xcd = flat & 7, slot = flat >> 3;
  const int m0 = (xcd + 8 * (slot & 3)) * 128;
  const int n0 = (slot >> 2) * 128;

  const int tid = threadIdx.x;
  const int wid = tid >> 6, lane = tid & 63;
  const int lr = lane & 15, lk8 = (lane >> 4) * 8;
  const int wm = (wid >> 1) * 64, wn = (wid & 1) * 64;

  f32x4 acc[4][4] = {};

  for (int kt = 0; kt < D_; kt += 32) {
#pragma unroll
    for (int i = 0; i < 2; ++i) {
      int li = tid + i * 256;
      int r = li >> 2, gg = li & 3;
      int4 a = *(const int4*)(Ab + (size_t)(m0 + r) * D_ + kt + gg * 8);
      *(int4*)&As[r][gg * 8] = a;
      int4 w = *(const int4*)(Wb + (size_t)(n0 + r) * D_ + kt + gg * 8);
      *(int4*)&Bs[r][gg * 8] = w;
    }
    __syncthreads();

    bf16x8 af[4], bf[4];
#pragma unroll
    for (int x = 0; x < 4; ++x) {
      af[x] = *(const bf16x8*)&As[wm + x * 16 + lr][lk8];
      bf[x] = *(const bf16x8*)&Bs[wn + x * 16 + lr][lk8];
    }
#pragma unroll
    for (int mi = 0; mi < 4; ++mi)
#pragma unroll
      for (int ni = 0; ni < 4; ++ni)
        acc[mi][ni] = __builtin_amdgcn_mfma_f32_16x16x32_bf16(
            af[mi], bf[ni], acc[mi][ni], 0, 0, 0);
    __syncthreads();
  }

#pragma unroll
  for (int mi = 0; mi < 4; ++mi)
#pragma unroll
    for (int ni = 0; ni < 4; ++ni) {
      int n = n0 + wn + ni * 16 + lr;
      float bv = bias[n];
#pragma unroll
      for (int j = 0; j < 4; ++j) {
        int mm = m0 + wm + mi * 16 + (lane >> 4) * 4 + j;
        outf[(size_t)mm * D_ + n] = acc[mi][ni][j] + bv;
      }
    }
}

// ---------------------------------------------------------------------------
extern "C" void kernel_launch(void* const* d_in, const int* in_sizes, int n_in,
                              void* d_out, int out_size, void* d_ws,
                              size_t ws_size, hipStream_t stream) {
  (void)in_sizes; (void)n_in; (void)out_size; (void)ws_size;
  const float* X  = (const float*)d_in[0];
  const float* Wq = (const float*)d_in[1];
  const float* bq = (const float*)d_in[2];
  const float* Wk = (const float*)d_in[3];
  const float* bk = (const float*)d_in[4];
  const float* Wv = (const float*)d_in[5];
  const float* bv = (const float*)d_in[6];
  const float* Wo = (const float*)d_in[7];
  const float* bo = (const float*)d_in[8];
  const int* pad    = (const int*)d_in[9];
  const int* causal = (const int*)d_in[10];

  float* out   = (float*)d_out;                       // [B,S,D] f32
  float* alpha = out + (size_t)2 * S_ * D_;           // [B,H,S,S] f32

  short* wsb = (short*)d_ws;
  const size_t MM = (size_t)1 << 20;                  // 1M shorts
  short* Xb   = wsb;                                  // 4M
  short* Wqb  = wsb + 4 * MM;                         // 1M each
  short* Wkb  = wsb + 5 * MM;
  short* Wvb  = wsb + 6 * MM;
  short* Wob  = wsb + 7 * MM;
  short* Qb   = wsb + 8 * MM;                         // 4M each
  short* Kb   = wsb + 12 * MM;
  short* VTb  = wsb + 16 * MM;
  short* ctxb = wsb + 20 * MM;                        // 4M
  float* padb = (float*)(wsb + 24 * MM);              // 4K f32

  dim3 blk(256);

  // X + weights -> bf16; padding bias
  k_cvt6<<<dim3(4096, 6), blk, 0, stream>>>(X, Wq, Wk, Wv, Wo, pad,
                                            Xb, Wqb, Wkb, Wvb, Wob, padb);

  // fused QKV projection (Q scaled to log2 domain; V written transposed)
  k_qkv<<<dim3(D_ / 128, M_ / 128, 3), blk, 0, stream>>>(
      Xb, Wqb, Wkb, Wvb, bq, bk, bv, Qb, Kb, VTb);

  // flash attention + alpha write (paired tiles, 64-col steps, XCD-aware)
  k_apv<<<dim3(NT_ * BH_ / 2), blk, 0, stream>>>(Qb, Kb, VTb, padb, causal,
                                                 alpha, ctxb);

  // output projection, XCD-swizzled
  k_oproj<<<dim3(D_ / 128, M_ / 128), blk, 0, stream>>>(ctxb, Wob, bo, out);
}